// Round 1
// baseline (1741.085 us; speedup 1.0000x reference)
//
#include <hip/hip_runtime.h>
#include <math.h>

// Problem constants (from reference)
#define NB   512   // batch
#define DIMD 256   // dim
#define CBN  256   // codewords per codebook
#define NCBK 8     // codebooks
#define NITR 5     // refinement iterations
#define TOPK 16    // K_CUTOFF

// pair index for m<n among 8 codebooks (28 pairs)
__device__ __forceinline__ int pidx(int m, int n) {
    return m * 8 - (m * (m + 1)) / 2 + (n - m - 1);
}

__device__ __forceinline__ bool kgt(double v1, int k1, double v2, int k2) {
    return (v1 > v2) || (v1 == v2 && k1 > k2);
}

// In-place bitonic sort of 256 (value,key) pairs in shared memory, ascending
// lexicographic by (value, key). Unique keys => exactly reproduces stable argsort.
__device__ void bitonic256(double* sv, int* sk, int tid) {
    for (int size = 2; size <= 256; size <<= 1) {
        for (int stride = size >> 1; stride > 0; stride >>= 1) {
            __syncthreads();
            int partner = tid ^ stride;
            if (partner > tid) {
                bool asc = ((tid & size) == 0);
                double v1 = sv[tid], v2 = sv[partner];
                int k1 = sk[tid], k2 = sk[partner];
                if (kgt(v1, k1, v2, k2) == asc) {
                    sv[tid] = v2; sk[tid] = k2;
                    sv[partner] = v1; sk[partner] = k1;
                }
            }
        }
    }
    __syncthreads();
}

// ---- Kernel 1: initial argmax of logits = (x @ W^T + bias) * scale ----
__global__ __launch_bounds__(256) void k_argmax(
        const float* __restrict__ x, const float* __restrict__ w,
        const float* __restrict__ bias, int* __restrict__ idx) {
    int n = blockIdx.x, b = blockIdx.y, j = threadIdx.x;
    __shared__ float sx[256];
    __shared__ double sv[256];
    __shared__ int sk[256];
    sx[j] = x[b * DIMD + j];
    __syncthreads();
    const float* wr = w + (size_t)(n * CBN + j) * DIMD;
    double acc = 0.0;
#pragma unroll 8
    for (int d = 0; d < DIMD; ++d) acc = fma((double)sx[d], (double)wr[d], acc);
    acc += (double)bias[n * CBN + j];  // *LOGITS_SCALE monotone, skip
    sv[j] = acc; sk[j] = j;
    __syncthreads();
    for (int s = 128; s > 0; s >>= 1) {
        if (j < s) {
            if (sv[j + s] > sv[j] || (sv[j + s] == sv[j] && sk[j + s] < sk[j])) {
                sv[j] = sv[j + s]; sk[j] = sk[j + s];
            }
        }
        __syncthreads();
    }
    if (j == 0) idx[b * NCBK + n] = sk[0];
}

// ---- Kernel 2: residual x_err[b][d] = sum_n c[n][idx]-x, and ||x_err||^2 ----
__global__ __launch_bounds__(256) void k_xerr(
        const float* __restrict__ x, const float* __restrict__ c,
        const int* __restrict__ idx, double* __restrict__ xerr,
        double* __restrict__ xes) {
    int b = blockIdx.x, d = threadIdx.x;
    __shared__ int si[NCBK];
    if (d < NCBK) si[d] = idx[b * NCBK + d];
    __syncthreads();
    double e = -(double)x[b * DIMD + d];
    for (int n = 0; n < NCBK; ++n)
        e += (double)c[((size_t)(n * CBN + si[n])) * DIMD + d];
    xerr[b * DIMD + d] = e;
    __shared__ double red[256];
    red[d] = e * e;
    __syncthreads();
    for (int s = 128; s > 0; s >>= 1) {
        if (d < s) red[d] += red[d + s];
        __syncthreads();
    }
    if (d == 0) xes[b] = red[0];
}

// ---- Kernel 3: per-(b,n) candidate costs + stable top-16 ----
__global__ __launch_bounds__(256) void k_cost(
        const float* __restrict__ c, const int* __restrict__ idx,
        const double* __restrict__ xerr,
        double* __restrict__ t16v, int* __restrict__ t16k) {
    int n = blockIdx.x, b = blockIdx.y, k = threadIdx.x;
    __shared__ double r[256];
    __shared__ double sv[256];
    __shared__ int sk[256];
    int old = idx[b * NCBK + n];
    // r = x_err - c_old
    r[k] = xerr[b * DIMD + k] - (double)c[((size_t)(n * CBN + old)) * DIMD + k];
    __syncthreads();
    const float* cr = c + (size_t)(n * CBN + k) * DIMD;
    double acc = 0.0;
#pragma unroll 8
    for (int d = 0; d < DIMD; ++d) {
        double t = r[d] + (double)cr[d];
        acc = fma(t, t, acc);
    }
    sv[k] = acc; sk[k] = k;
    bitonic256(sv, sk, k);
    if (k < TOPK) {
        t16v[(b * NCBK + n) * TOPK + k] = sv[k];
        t16k[(b * NCBK + n) * TOPK + k] = sk[k];
    }
}

// ---- Kernel 4: Gram matrices D[b][p][i][j] = delta_m(i) . delta_n(j) ----
__global__ __launch_bounds__(256) void k_dmat(
        const float* __restrict__ c, const int* __restrict__ idx,
        const int* __restrict__ t16k, float* __restrict__ D) {
    int p = blockIdx.x, b = blockIdx.y, tid = threadIdx.x;
    // decode pair p -> (m, n), m < n
    int pp = p, m = 0;
    while (pp >= 7 - m) { pp -= 7 - m; ++m; }
    int n = m + 1 + pp;

    __shared__ float em[16 * 257];
    __shared__ float on[16 * 257];
    __shared__ int km[16], kn[16];
    if (tid < 16) km[tid] = t16k[(b * NCBK + m) * TOPK + tid];
    else if (tid < 32) kn[tid - 16] = t16k[(b * NCBK + n) * TOPK + (tid - 16)];
    __syncthreads();
    int oldm = idx[b * NCBK + m], oldn = idx[b * NCBK + n];
    float com = c[((size_t)(m * CBN + oldm)) * DIMD + tid];
    float con = c[((size_t)(n * CBN + oldn)) * DIMD + tid];
    for (int r = 0; r < 16; ++r) {
        em[r * 257 + tid] = c[((size_t)(m * CBN + km[r])) * DIMD + tid] - com;
        on[r * 257 + tid] = c[((size_t)(n * CBN + kn[r])) * DIMD + tid] - con;
    }
    __syncthreads();
    int i = tid >> 4, j = tid & 15;
    double acc = 0.0;
#pragma unroll 8
    for (int d = 0; d < DIMD; ++d)
        acc = fma((double)em[i * 257 + d], (double)on[j * 257 + d], acc);
    D[((size_t)(b * 28 + p)) * 256 + tid] = (float)acc;
}

// ---- Kernel 5: 3-level merge tournament per batch row ----
__global__ __launch_bounds__(256) void k_tourney(
        const double* __restrict__ t16v, const int* __restrict__ t16k,
        const float* __restrict__ D, const double* __restrict__ xesArr,
        int* __restrict__ idx, int* __restrict__ out) {
    int b = blockIdx.x, tid = threadIdx.x;
    __shared__ double tv[NCBK][16];
    __shared__ int tk[NCBK][16];
    __shared__ double l1v[4][16];
    __shared__ int l1k[4][16];
    __shared__ double l2v[2][16];
    __shared__ int l2k[2][16];
    __shared__ double sv[256];
    __shared__ int sk[256];
    if (tid < 128) {
        tv[tid >> 4][tid & 15] = t16v[b * 128 + tid];
        tk[tid >> 4][tid & 15] = t16k[b * 128 + tid];
    }
    double xes = xesArr[b];
    __syncthreads();
    const float* Db = D + (size_t)b * 28 * 256;

    // Level 1: merge codebook pairs (2g, 2g+1); combo k = i*16 + j (even slot i, odd slot j)
    for (int g = 0; g < 4; ++g) {
        int i = tid >> 4, j = tid & 15;
        double val = tv[2 * g][i] + tv[2 * g + 1][j] - xes
                   + 2.0 * (double)Db[pidx(2 * g, 2 * g + 1) * 256 + tid];
        sv[tid] = val; sk[tid] = tid;
        bitonic256(sv, sk, tid);
        if (tid < 16) { l1v[g][tid] = sv[tid]; l1k[g][tid] = sk[tid]; }
        __syncthreads();
    }
    // Level 2: merge groups (2G, 2G+1) covering codebooks 4G..4G+3
    for (int G = 0; G < 2; ++G) {
        int a = tid >> 4, b2 = tid & 15;
        int pe = l1k[2 * G][a], po = l1k[2 * G + 1][b2];
        int ie = pe >> 4, io = pe & 15, je = po >> 4, jo = po & 15;
        int c0 = 4 * G, c1 = 4 * G + 1, c2 = 4 * G + 2, c3 = 4 * G + 3;
        double cross = (double)Db[pidx(c0, c2) * 256 + ie * 16 + je]
                     + (double)Db[pidx(c0, c3) * 256 + ie * 16 + jo]
                     + (double)Db[pidx(c1, c2) * 256 + io * 16 + je]
                     + (double)Db[pidx(c1, c3) * 256 + io * 16 + jo];
        double val = l1v[2 * G][a] + l1v[2 * G + 1][b2] - xes + 2.0 * cross;
        sv[tid] = val; sk[tid] = tid;
        bitonic256(sv, sk, tid);
        if (tid < 16) {
            l2v[G][tid] = sv[tid];
            int kk = sk[tid];
            l2k[G][tid] = (l1k[2 * G][kk >> 4] << 8) | l1k[2 * G + 1][kk & 15];
        }
        __syncthreads();
    }
    // Level 3: final merge + argmin (stable: min value, then min combo index)
    {
        int a = tid >> 4, b2 = tid & 15;
        int p0 = l2k[0][a], p1 = l2k[1][b2];
        int se[4] = { (p0 >> 12) & 15, (p0 >> 8) & 15, (p0 >> 4) & 15, p0 & 15 };
        int so[4] = { (p1 >> 12) & 15, (p1 >> 8) & 15, (p1 >> 4) & 15, p1 & 15 };
        double cross = 0.0;
        for (int mm = 0; mm < 4; ++mm)
            for (int q = 0; q < 4; ++q)
                cross += (double)Db[pidx(mm, 4 + q) * 256 + se[mm] * 16 + so[q]];
        double val = l2v[0][a] + l2v[1][b2] - xes + 2.0 * cross;
        sv[tid] = val; sk[tid] = tid;
        bitonic256(sv, sk, tid);
        if (tid == 0) {
            int k = sk[0];
            int a0 = k >> 4, b0 = k & 15;
            int p0w = l2k[0][a0], p1w = l2k[1][b0];
            int sl[8] = { (p0w >> 12) & 15, (p0w >> 8) & 15, (p0w >> 4) & 15, p0w & 15,
                          (p1w >> 12) & 15, (p1w >> 8) & 15, (p1w >> 4) & 15, p1w & 15 };
            for (int n = 0; n < NCBK; ++n) {
                int ci = tk[n][sl[n]];
                idx[b * NCBK + n] = ci;
                if (out) out[b * NCBK + n] = ci;
            }
        }
    }
}

extern "C" void kernel_launch(void* const* d_in, const int* in_sizes, int n_in,
                              void* d_out, int out_size, void* d_ws, size_t ws_size,
                              hipStream_t stream) {
    const float* x    = (const float*)d_in[0];  // (512, 256)
    const float* w    = (const float*)d_in[1];  // (2048, 256)
    const float* bias = (const float*)d_in[2];  // (2048,)
    const float* c    = (const float*)d_in[3];  // (2048, 256)
    int* out = (int*)d_out;                     // (512, 8) int32
    char* ws = (char*)d_ws;

    // workspace layout (16.5 MB total)
    double* xerr = (double*)(ws);                 // 512*256*8 = 1,048,576
    double* xes  = (double*)(ws + 1048576);       // 512*8     = 4,096
    double* t16v = (double*)(ws + 1052672);       // 512*8*16*8= 524,288
    float*  D    = (float*) (ws + 1576960);       // 512*28*256*4 = 14,680,064
    int*    t16k = (int*)   (ws + 16257024);      // 512*8*16*4 = 262,144
    int*    idx  = (int*)   (ws + 16519168);      // 512*8*4   = 16,384

    k_argmax<<<dim3(NCBK, NB), 256, 0, stream>>>(x, w, bias, idx);
    for (int it = 0; it < NITR; ++it) {
        k_xerr<<<NB, 256, 0, stream>>>(x, c, idx, xerr, xes);
        k_cost<<<dim3(NCBK, NB), 256, 0, stream>>>(c, idx, xerr, t16v, t16k);
        k_dmat<<<dim3(28, NB), 256, 0, stream>>>(c, idx, t16k, D);
        k_tourney<<<NB, 256, 0, stream>>>(t16v, t16k, D, xes, idx,
                                          (it == NITR - 1) ? out : nullptr);
    }
}

// Round 2
// 755.151 us; speedup vs baseline: 2.3056x; 2.3056x over previous
//
#include <hip/hip_runtime.h>
#include <math.h>

// Problem constants (from reference)
#define NB   512   // batch
#define DIMD 256   // dim
#define CBN  256   // codewords per codebook
#define NCBK 8     // codebooks
#define NITR 5     // refinement iterations
#define TOPK 16    // K_CUTOFF

// pair index for m<n among 8 codebooks (28 pairs)
__device__ __forceinline__ int pidx(int m, int n) {
    return m * 8 - (m * (m + 1)) / 2 + (n - m - 1);
}

__device__ __forceinline__ bool kgt(double v1, int k1, double v2, int k2) {
    return (v1 > v2) || (v1 == v2 && k1 > k2);
}

// In-place bitonic sort of 256 (value,key) pairs in shared memory, ascending
// lexicographic by (value, key). Unique keys => exactly reproduces stable argsort.
__device__ void bitonic256(double* sv, int* sk, int tid) {
    for (int size = 2; size <= 256; size <<= 1) {
        for (int stride = size >> 1; stride > 0; stride >>= 1) {
            __syncthreads();
            int partner = tid ^ stride;
            if (partner > tid) {
                bool asc = ((tid & size) == 0);
                double v1 = sv[tid], v2 = sv[partner];
                int k1 = sk[tid], k2 = sk[partner];
                if (kgt(v1, k1, v2, k2) == asc) {
                    sv[tid] = v2; sk[tid] = k2;
                    sv[partner] = v1; sk[partner] = k1;
                }
            }
        }
    }
    __syncthreads();
}

// ---- GEMM: Out[i][j] = sum_k A[i][k]*B[j][k], fp32 in, fp64 out, K=256 ----
// 64x64 tile per block, 256 threads, 4x4 accumulators/thread.
__global__ __launch_bounds__(256) void k_gemm_nt(
        const float* __restrict__ A, const float* __restrict__ B,
        double* __restrict__ Out, int ldo) {
    __shared__ float As[64][17];
    __shared__ float Bs[64][17];
    int tid = threadIdx.x;
    int ty = tid >> 4, tx = tid & 15;
    int row0 = blockIdx.y * 64, col0 = blockIdx.x * 64;
    int lr = tid >> 2, lk = (tid & 3) * 4;
    double acc[4][4] = {};
    for (int k0 = 0; k0 < DIMD; k0 += 16) {
        float4 av = *(const float4*)(A + (size_t)(row0 + lr) * DIMD + k0 + lk);
        float4 bv = *(const float4*)(B + (size_t)(col0 + lr) * DIMD + k0 + lk);
        __syncthreads();
        As[lr][lk + 0] = av.x; As[lr][lk + 1] = av.y;
        As[lr][lk + 2] = av.z; As[lr][lk + 3] = av.w;
        Bs[lr][lk + 0] = bv.x; Bs[lr][lk + 1] = bv.y;
        Bs[lr][lk + 2] = bv.z; Bs[lr][lk + 3] = bv.w;
        __syncthreads();
#pragma unroll 4
        for (int kk = 0; kk < 16; ++kk) {
            double a[4], b[4];
#pragma unroll
            for (int i = 0; i < 4; ++i) a[i] = (double)As[4 * ty + i][kk];
#pragma unroll
            for (int j = 0; j < 4; ++j) b[j] = (double)Bs[4 * tx + j][kk];
#pragma unroll
            for (int i = 0; i < 4; ++i)
#pragma unroll
                for (int j = 0; j < 4; ++j) acc[i][j] = fma(a[i], b[j], acc[i][j]);
        }
    }
#pragma unroll
    for (int i = 0; i < 4; ++i)
#pragma unroll
        for (int j = 0; j < 4; ++j)
            Out[(size_t)(row0 + 4 * ty + i) * ldo + col0 + 4 * tx + j] = acc[i][j];
}

// ---- Gdiag[j] = G[j][j] ----
__global__ __launch_bounds__(256) void k_gdiag(const double* __restrict__ G,
                                               double* __restrict__ Gdiag) {
    int j = blockIdx.x * 256 + threadIdx.x;
    Gdiag[j] = G[(size_t)j * (NCBK * CBN) + j];
}

// ---- initial argmax from Xw + bias (LOGITS_SCALE monotone, skipped) ----
__global__ __launch_bounds__(256) void k_argmax2(
        const double* __restrict__ Xw, const float* __restrict__ bias,
        int* __restrict__ idx) {
    int n = blockIdx.x, b = blockIdx.y, j = threadIdx.x;
    __shared__ double sv[256];
    __shared__ int sk[256];
    sv[j] = Xw[(size_t)b * (NCBK * CBN) + n * CBN + j] + (double)bias[n * CBN + j];
    sk[j] = j;
    __syncthreads();
    for (int s = 128; s > 0; s >>= 1) {
        if (j < s) {
            if (sv[j + s] > sv[j] || (sv[j + s] == sv[j] && sk[j + s] < sk[j])) {
                sv[j] = sv[j + s]; sk[j] = sk[j + s];
            }
        }
        __syncthreads();
    }
    if (j == 0) idx[b * NCBK + n] = sk[0];
}

// ---- per-iteration prep: jrow, xes (=||x_err||^2), rss[b][n] (=||r_n||^2) ----
__global__ __launch_bounds__(256) void k_prep(
        const float* __restrict__ x, const double* __restrict__ G,
        const double* __restrict__ Xc, const double* __restrict__ Gdiag,
        const int* __restrict__ idx, int* __restrict__ jrow,
        double* __restrict__ xes, double* __restrict__ rss) {
    int b = blockIdx.x, tid = threadIdx.x;
    __shared__ int jm[NCBK];
    __shared__ double red[256];
    __shared__ double gmat[64];
    __shared__ double Sj[NCBK], Xcj[NCBK];
    __shared__ double e_sh;
    if (tid < NCBK) jm[tid] = tid * CBN + idx[b * NCBK + tid];
    double xv = (double)x[b * DIMD + tid];
    red[tid] = xv * xv;
    __syncthreads();
    if (tid < 64) gmat[tid] = G[(size_t)jm[tid >> 3] * (NCBK * CBN) + jm[tid & 7]];
    if (tid >= 64 && tid < 72) Xcj[tid - 64] = Xc[(size_t)b * (NCBK * CBN) + jm[tid - 64]];
    for (int s = 128; s > 0; s >>= 1) {
        __syncthreads();
        if (tid < s) red[tid] += red[tid + s];
    }
    __syncthreads();
    if (tid < NCBK) {
        double s = 0.0;
        for (int mp = 0; mp < NCBK; ++mp) s += gmat[mp * 8 + tid];
        Sj[tid] = s - Xcj[tid];
    }
    __syncthreads();
    if (tid == 0) {
        double e = red[0];
        for (int m = 0; m < NCBK; ++m) e += Sj[m] - Xcj[m];
        e_sh = e;
        xes[b] = e;
    }
    __syncthreads();
    if (tid < NCBK) {
        jrow[b * NCBK + tid] = jm[tid];
        rss[b * NCBK + tid] = e_sh - 2.0 * Sj[tid] + Gdiag[jm[tid]];
    }
}

// ---- candidate costs from G rows + stable top-16 ----
__global__ __launch_bounds__(256) void k_cost2(
        const double* __restrict__ G, const double* __restrict__ Xc,
        const double* __restrict__ Gdiag, const int* __restrict__ jrow,
        const double* __restrict__ rss,
        double* __restrict__ t16v, int* __restrict__ t16k) {
    int n = blockIdx.x, b = blockIdx.y, tid = threadIdx.x;
    __shared__ double sv[256];
    __shared__ int sk[256];
    __shared__ int jm[NCBK];
    if (tid < NCBK) jm[tid] = jrow[b * NCBK + tid];
    __syncthreads();
    int kp = n * CBN + tid;
    double s = -Xc[(size_t)b * (NCBK * CBN) + kp];
    double gjn = 0.0;
#pragma unroll
    for (int m = 0; m < NCBK; ++m) {
        double g = G[(size_t)jm[m] * (NCBK * CBN) + kp];
        s += g;
        if (m == n) gjn = g;
    }
    double cost = rss[b * NCBK + n] + 2.0 * (s - gjn) + Gdiag[kp];
    sv[tid] = cost; sk[tid] = tid;
    bitonic256(sv, sk, tid);
    if (tid < TOPK) {
        t16v[(b * NCBK + n) * TOPK + tid] = sv[tid];
        t16k[(b * NCBK + n) * TOPK + tid] = sk[tid];
    }
}

// ---- Gram of deltas via G gathers: D[b][p][i][j] = delta_m(i).delta_n(j) ----
__global__ __launch_bounds__(256) void k_dmat2(
        const double* __restrict__ G, const int* __restrict__ jrow,
        const int* __restrict__ t16k, float* __restrict__ D) {
    int p = blockIdx.x, b = blockIdx.y, tid = threadIdx.x;
    int pp = p, m = 0;
    while (pp >= 7 - m) { pp -= 7 - m; ++m; }
    int n = m + 1 + pp;
    __shared__ int am[TOPK], bn[TOPK];
    if (tid < TOPK) am[tid] = m * CBN + t16k[(b * NCBK + m) * TOPK + tid];
    else if (tid < 2 * TOPK) bn[tid - TOPK] = n * CBN + t16k[(b * NCBK + n) * TOPK + (tid - TOPK)];
    __syncthreads();
    int jm = jrow[b * NCBK + m], jn = jrow[b * NCBK + n];
    int i = tid >> 4, j = tid & 15;
    const size_t W = NCBK * CBN;
    double v = G[(size_t)am[i] * W + bn[j]] - G[(size_t)am[i] * W + jn]
             - G[(size_t)jm * W + bn[j]] + G[(size_t)jm * W + jn];
    D[((size_t)(b * 28 + p)) * 256 + tid] = (float)v;
}

// ---- 3-level merge tournament per batch row (unchanged from round 1) ----
__global__ __launch_bounds__(256) void k_tourney(
        const double* __restrict__ t16v, const int* __restrict__ t16k,
        const float* __restrict__ D, const double* __restrict__ xesArr,
        int* __restrict__ idx, int* __restrict__ out) {
    int b = blockIdx.x, tid = threadIdx.x;
    __shared__ double tv[NCBK][16];
    __shared__ int tk[NCBK][16];
    __shared__ double l1v[4][16];
    __shared__ int l1k[4][16];
    __shared__ double l2v[2][16];
    __shared__ int l2k[2][16];
    __shared__ double sv[256];
    __shared__ int sk[256];
    if (tid < 128) {
        tv[tid >> 4][tid & 15] = t16v[b * 128 + tid];
        tk[tid >> 4][tid & 15] = t16k[b * 128 + tid];
    }
    double xes = xesArr[b];
    __syncthreads();
    const float* Db = D + (size_t)b * 28 * 256;

    for (int g = 0; g < 4; ++g) {
        int i = tid >> 4, j = tid & 15;
        double val = tv[2 * g][i] + tv[2 * g + 1][j] - xes
                   + 2.0 * (double)Db[pidx(2 * g, 2 * g + 1) * 256 + tid];
        sv[tid] = val; sk[tid] = tid;
        bitonic256(sv, sk, tid);
        if (tid < 16) { l1v[g][tid] = sv[tid]; l1k[g][tid] = sk[tid]; }
        __syncthreads();
    }
    for (int G2 = 0; G2 < 2; ++G2) {
        int a = tid >> 4, b2 = tid & 15;
        int pe = l1k[2 * G2][a], po = l1k[2 * G2 + 1][b2];
        int ie = pe >> 4, io = pe & 15, je = po >> 4, jo = po & 15;
        int c0 = 4 * G2, c1 = 4 * G2 + 1, c2 = 4 * G2 + 2, c3 = 4 * G2 + 3;
        double cross = (double)Db[pidx(c0, c2) * 256 + ie * 16 + je]
                     + (double)Db[pidx(c0, c3) * 256 + ie * 16 + jo]
                     + (double)Db[pidx(c1, c2) * 256 + io * 16 + je]
                     + (double)Db[pidx(c1, c3) * 256 + io * 16 + jo];
        double val = l1v[2 * G2][a] + l1v[2 * G2 + 1][b2] - xes + 2.0 * cross;
        sv[tid] = val; sk[tid] = tid;
        bitonic256(sv, sk, tid);
        if (tid < 16) {
            l2v[G2][tid] = sv[tid];
            int kk = sk[tid];
            l2k[G2][tid] = (l1k[2 * G2][kk >> 4] << 8) | l1k[2 * G2 + 1][kk & 15];
        }
        __syncthreads();
    }
    {
        int a = tid >> 4, b2 = tid & 15;
        int p0 = l2k[0][a], p1 = l2k[1][b2];
        int se[4] = { (p0 >> 12) & 15, (p0 >> 8) & 15, (p0 >> 4) & 15, p0 & 15 };
        int so[4] = { (p1 >> 12) & 15, (p1 >> 8) & 15, (p1 >> 4) & 15, p1 & 15 };
        double cross = 0.0;
        for (int mm = 0; mm < 4; ++mm)
            for (int q = 0; q < 4; ++q)
                cross += (double)Db[pidx(mm, 4 + q) * 256 + se[mm] * 16 + so[q]];
        double val = l2v[0][a] + l2v[1][b2] - xes + 2.0 * cross;
        sv[tid] = val; sk[tid] = tid;
        bitonic256(sv, sk, tid);
        if (tid == 0) {
            int k = sk[0];
            int a0 = k >> 4, b0 = k & 15;
            int p0w = l2k[0][a0], p1w = l2k[1][b0];
            int sl[8] = { (p0w >> 12) & 15, (p0w >> 8) & 15, (p0w >> 4) & 15, p0w & 15,
                          (p1w >> 12) & 15, (p1w >> 8) & 15, (p1w >> 4) & 15, p1w & 15 };
            for (int n = 0; n < NCBK; ++n) {
                int ci = tk[n][sl[n]];
                idx[b * NCBK + n] = ci;
                if (out) out[b * NCBK + n] = ci;
            }
        }
    }
}

extern "C" void kernel_launch(void* const* d_in, const int* in_sizes, int n_in,
                              void* d_out, int out_size, void* d_ws, size_t ws_size,
                              hipStream_t stream) {
    const float* x    = (const float*)d_in[0];  // (512, 256)
    const float* w    = (const float*)d_in[1];  // (2048, 256)
    const float* bias = (const float*)d_in[2];  // (2048,)
    const float* c    = (const float*)d_in[3];  // (2048, 256)
    int* out = (int*)d_out;                     // (512, 8) int32
    char* ws = (char*)d_ws;

    // workspace layout (~63 MB)
    double* G     = (double*)(ws);               // 2048*2048*8 = 33,554,432
    double* Xc    = (double*)(ws + 33554432);    // 512*2048*8 = 8,388,608
    double* Xw    = (double*)(ws + 41943040);    // 512*2048*8 = 8,388,608
    double* Gdiag = (double*)(ws + 50331648);    // 2048*8     = 16,384
    double* t16v  = (double*)(ws + 50348032);    // 512*8*16*8 = 524,288
    float*  D     = (float*) (ws + 50872320);    // 512*28*256*4 = 14,680,064
    int*    t16k  = (int*)   (ws + 65552384);    // 512*8*16*4 = 262,144
    int*    jrow  = (int*)   (ws + 65814528);    // 512*8*4    = 16,384
    int*    idx   = (int*)   (ws + 65830912);    // 512*8*4    = 16,384
    double* xes   = (double*)(ws + 65847296);    // 512*8      = 4,096
    double* rss   = (double*)(ws + 65851392);    // 512*8*8    = 32,768

    // One-time (per call): Gram + projections + diag + initial argmax
    k_gemm_nt<<<dim3(32, 8),  256, 0, stream>>>(x, w, Xw, NCBK * CBN);
    k_gemm_nt<<<dim3(32, 8),  256, 0, stream>>>(x, c, Xc, NCBK * CBN);
    k_gemm_nt<<<dim3(32, 32), 256, 0, stream>>>(c, c, G,  NCBK * CBN);
    k_gdiag<<<8, 256, 0, stream>>>(G, Gdiag);
    k_argmax2<<<dim3(NCBK, NB), 256, 0, stream>>>(Xw, bias, idx);

    for (int it = 0; it < NITR; ++it) {
        k_prep<<<NB, 256, 0, stream>>>(x, G, Xc, Gdiag, idx, jrow, xes, rss);
        k_cost2<<<dim3(NCBK, NB), 256, 0, stream>>>(G, Xc, Gdiag, jrow, rss, t16v, t16k);
        k_dmat2<<<dim3(28, NB), 256, 0, stream>>>(G, jrow, t16k, D);
        k_tourney<<<NB, 256, 0, stream>>>(t16v, t16k, D, xes, idx,
                                          (it == NITR - 1) ? out : nullptr);
    }
}

// Round 3
// 557.809 us; speedup vs baseline: 3.1213x; 1.3538x over previous
//
#include <hip/hip_runtime.h>
#include <math.h>

// Problem constants (from reference)
#define NB   512   // batch
#define DIMD 256   // dim
#define CBN  256   // codewords per codebook
#define NCBK 8     // codebooks
#define NITR 5     // refinement iterations
#define TOPK 16    // K_CUTOFF
#define W2   2048  // NCBK*CBN

// pair index for m<n among 8 codebooks (28 pairs)
__device__ __forceinline__ int pidx(int m, int n) {
    return m * 8 - (m * (m + 1)) / 2 + (n - m - 1);
}

__device__ const int PM28[28] = {0,0,0,0,0,0,0, 1,1,1,1,1,1, 2,2,2,2,2, 3,3,3,3, 4,4,4, 5,5, 6};
__device__ const int PN28[28] = {1,2,3,4,5,6,7, 2,3,4,5,6,7, 3,4,5,6,7, 4,5,6,7, 5,6,7, 6,7, 7};

__device__ __forceinline__ bool kgt(double v1, int k1, double v2, int k2) {
    return (v1 > v2) || (v1 == v2 && k1 > k2);
}

// Bitonic sort of 64 (v,k) pairs, one per lane, ascending by (v,k). No barriers.
__device__ __forceinline__ void wave_sort64(double& v, int& k, int lane) {
#pragma unroll
    for (int size = 2; size <= 64; size <<= 1) {
#pragma unroll
        for (int stride = size >> 1; stride > 0; stride >>= 1) {
            double pv = __shfl_xor(v, stride, 64);
            int pk = __shfl_xor(k, stride, 64);
            bool asc = ((lane & size) == 0);   // (lane&64)==0 always -> final asc
            bool lower = (lane & stride) == 0;
            bool gt = kgt(v, k, pv, pk);
            bool take = asc ? (lower ? gt : !gt) : (lower ? !gt : gt);
            if (take) { v = pv; k = pk; }
        }
    }
}

// Stable top-16 of 256 (v,k) pairs (one per thread, 4 waves).
// Result (ascending) in outV/outK[0..15]. cv/ck are 64-entry shared scratch.
// Ends with __syncthreads so outputs are visible to all threads.
__device__ __forceinline__ void top16_256(double v, int k, int tid,
                                          double* cv, int* ck,
                                          double* outV, int* outK) {
    int lane = tid & 63, wave = tid >> 6;
    wave_sort64(v, k, lane);
    if (lane < 16) { cv[wave * 16 + lane] = v; ck[wave * 16 + lane] = k; }
    __syncthreads();
    if (wave == 0) {
        double mv = cv[lane]; int mk = ck[lane];
        wave_sort64(mv, mk, lane);
        if (lane < 16) { outV[lane] = mv; outK[lane] = mk; }
    }
    __syncthreads();
}

// ---- GEMM: Out[i][j] = sum_k A[i][k]*B[j][k], fp32 in, fp64 out, K=256 ----
__global__ __launch_bounds__(256) void k_gemm_nt(
        const float* __restrict__ A, const float* __restrict__ B,
        double* __restrict__ Out, int ldo) {
    __shared__ float As[64][17];
    __shared__ float Bs[64][17];
    int tid = threadIdx.x;
    int ty = tid >> 4, tx = tid & 15;
    int row0 = blockIdx.y * 64, col0 = blockIdx.x * 64;
    int lr = tid >> 2, lk = (tid & 3) * 4;
    double acc[4][4] = {};
    for (int k0 = 0; k0 < DIMD; k0 += 16) {
        float4 av = *(const float4*)(A + (size_t)(row0 + lr) * DIMD + k0 + lk);
        float4 bv = *(const float4*)(B + (size_t)(col0 + lr) * DIMD + k0 + lk);
        __syncthreads();
        As[lr][lk + 0] = av.x; As[lr][lk + 1] = av.y;
        As[lr][lk + 2] = av.z; As[lr][lk + 3] = av.w;
        Bs[lr][lk + 0] = bv.x; Bs[lr][lk + 1] = bv.y;
        Bs[lr][lk + 2] = bv.z; Bs[lr][lk + 3] = bv.w;
        __syncthreads();
#pragma unroll 4
        for (int kk = 0; kk < 16; ++kk) {
            double a[4], b[4];
#pragma unroll
            for (int i = 0; i < 4; ++i) a[i] = (double)As[4 * ty + i][kk];
#pragma unroll
            for (int j = 0; j < 4; ++j) b[j] = (double)Bs[4 * tx + j][kk];
#pragma unroll
            for (int i = 0; i < 4; ++i)
#pragma unroll
                for (int j = 0; j < 4; ++j) acc[i][j] = fma(a[i], b[j], acc[i][j]);
        }
    }
#pragma unroll
    for (int i = 0; i < 4; ++i)
#pragma unroll
        for (int j = 0; j < 4; ++j)
            Out[(size_t)(row0 + 4 * ty + i) * ldo + col0 + 4 * tx + j] = acc[i][j];
}

// ---- Gdiag[j] = G[j][j] ----
__global__ __launch_bounds__(256) void k_gdiag(const double* __restrict__ G,
                                               double* __restrict__ Gdiag) {
    int j = blockIdx.x * 256 + threadIdx.x;
    Gdiag[j] = G[(size_t)j * W2 + j];
}

// ---- xnorm[b] = ||x_b||^2 (fp64), one wave per row ----
__global__ __launch_bounds__(64) void k_xnorm(const float* __restrict__ x,
                                              double* __restrict__ xn) {
    int b = blockIdx.x, lane = threadIdx.x;
    float4 v = *(const float4*)(x + (size_t)b * DIMD + lane * 4);
    double s = (double)v.x * v.x + (double)v.y * v.y
             + (double)v.z * v.z + (double)v.w * v.w;
#pragma unroll
    for (int st = 32; st > 0; st >>= 1) s += __shfl_down(s, st, 64);
    if (lane == 0) xn[b] = s;
}

// ---- initial argmax from Xw + bias ----
__global__ __launch_bounds__(256) void k_argmax2(
        const double* __restrict__ Xw, const float* __restrict__ bias,
        int* __restrict__ idx) {
    int n = blockIdx.x, b = blockIdx.y, j = threadIdx.x;
    __shared__ double sv[256];
    __shared__ int sk[256];
    sv[j] = Xw[(size_t)b * W2 + n * CBN + j] + (double)bias[n * CBN + j];
    sk[j] = j;
    __syncthreads();
    for (int s = 128; s > 0; s >>= 1) {
        if (j < s) {
            if (sv[j + s] > sv[j] || (sv[j + s] == sv[j] && sk[j + s] < sk[j])) {
                sv[j] = sv[j + s]; sk[j] = sk[j + s];
            }
        }
        __syncthreads();
    }
    if (j == 0) idx[b * NCBK + n] = sk[0];
}

// ---- fused candidate costs + stable top-16 (k_prep folded in) ----
__global__ __launch_bounds__(256) void k_cost3(
        const double* __restrict__ G, const double* __restrict__ Xc,
        const double* __restrict__ Gdiag, const double* __restrict__ xnorm,
        const int* __restrict__ idx,
        double* __restrict__ t16v, int* __restrict__ t16k) {
    int n = blockIdx.x, b = blockIdx.y, tid = threadIdx.x;
    __shared__ int jm[NCBK];
    __shared__ double gmat[64], Xcj[NCBK], Sj[NCBK];
    __shared__ double rss_sh;
    __shared__ double cv[64]; __shared__ int ck[64];
    __shared__ double outV[16]; __shared__ int outK[16];
    if (tid < NCBK) jm[tid] = tid * CBN + idx[b * NCBK + tid];
    __syncthreads();
    if (tid < 64) gmat[tid] = G[(size_t)jm[tid >> 3] * W2 + jm[tid & 7]];
    else if (tid < 72) Xcj[tid - 64] = Xc[(size_t)b * W2 + jm[tid - 64]];
    __syncthreads();
    if (tid < NCBK) {
        double s = 0.0;
        for (int mp = 0; mp < NCBK; ++mp) s += gmat[mp * 8 + tid];
        Sj[tid] = s - Xcj[tid];
    }
    __syncthreads();
    if (tid == 0) {
        double e = xnorm[b];
        for (int m = 0; m < NCBK; ++m) e += Sj[m] - Xcj[m];
        rss_sh = e - 2.0 * Sj[n] + Gdiag[jm[n]];
    }
    __syncthreads();
    int kp = n * CBN + tid;
    double s = -Xc[(size_t)b * W2 + kp];
    double gjn = 0.0;
#pragma unroll
    for (int m = 0; m < NCBK; ++m) {
        double g = G[(size_t)jm[m] * W2 + kp];
        s += g;
        if (m == n) gjn = g;
    }
    double cost = rss_sh + 2.0 * (s - gjn) + Gdiag[kp];
    top16_256(cost, tid, tid, cv, ck, outV, outK);
    if (tid < TOPK) {
        t16v[(b * NCBK + n) * TOPK + tid] = outV[tid];
        t16k[(b * NCBK + n) * TOPK + tid] = outK[tid];
    }
}

// ---- fused D-tiles (in LDS) + 3-level tournament ----
__global__ __launch_bounds__(256) void k_tourney3(
        const double* __restrict__ G, const double* __restrict__ Xc,
        const double* __restrict__ xnorm,
        const double* __restrict__ t16v, const int* __restrict__ t16k,
        int* __restrict__ idx, int* __restrict__ out) {
    int b = blockIdx.x, tid = threadIdx.x;
    __shared__ float Dsh[28 * 256];        // 28 KB
    __shared__ double Ecr[NCBK * NCBK * 16]; // 8 KB: Ecr[m][n][i] = G[am[m][i]][jm[n]]
    __shared__ int jm[NCBK];
    __shared__ double gmat[64], Xcj[NCBK];
    __shared__ double xes_sh;
    __shared__ double tv[NCBK][16];
    __shared__ int tk[NCBK][16];
    __shared__ int amr[NCBK][16];
    __shared__ double l1v[4][16]; __shared__ int l1k[4][16];
    __shared__ double l2v[2][16]; __shared__ int l2k[2][16];
    __shared__ double cv[64]; __shared__ int ck[64];
    __shared__ double tmpV[16]; __shared__ int tmpK[16];

    if (tid < 128) {
        int m = tid >> 4, i = tid & 15;
        double tvv = t16v[b * 128 + tid];
        int tkk = t16k[b * 128 + tid];
        tv[m][i] = tvv; tk[m][i] = tkk; amr[m][i] = m * CBN + tkk;
    } else if (tid < 136) {
        int m = tid - 128;
        jm[m] = m * CBN + idx[b * NCBK + m];
    }
    __syncthreads();
    if (tid < 64) gmat[tid] = G[(size_t)jm[tid >> 3] * W2 + jm[tid & 7]];
    else if (tid < 72) Xcj[tid - 64] = Xc[(size_t)b * W2 + jm[tid - 64]];
    for (int t = tid; t < NCBK * NCBK * 16; t += 256) {
        int m = t >> 7, nn = (t >> 4) & 7, ii = t & 15;
        Ecr[t] = G[(size_t)amr[m][ii] * W2 + jm[nn]];
    }
    __syncthreads();
    if (tid == 0) {
        // xes = xnorm + sum_m (Sj[m] - Xcj[m]); Sj[m] = colsum_m - Xcj[m]
        double e = xnorm[b];
        for (int t2 = 0; t2 < 8; ++t2) {
            double s = 0.0;
            for (int mp = 0; mp < 8; ++mp) s += gmat[mp * 8 + t2];
            e += s - 2.0 * Xcj[t2];
        }
        xes_sh = e;
    }
    {
        int i = tid >> 4, j = tid & 15;
        for (int p = 0; p < 28; ++p) {
            int m = PM28[p], n = PN28[p];
            double v = G[(size_t)amr[m][i] * W2 + amr[n][j]]
                     - Ecr[m * 128 + n * 16 + i]
                     - Ecr[n * 128 + m * 16 + j]
                     + gmat[m * 8 + n];
            Dsh[p * 256 + tid] = (float)v;
        }
    }
    __syncthreads();
    double xes = xes_sh;

    // Level 1: merge codebook pairs (2g, 2g+1)
    for (int g = 0; g < 4; ++g) {
        int i = tid >> 4, j = tid & 15;
        double val = tv[2 * g][i] + tv[2 * g + 1][j] - xes
                   + 2.0 * (double)Dsh[pidx(2 * g, 2 * g + 1) * 256 + tid];
        top16_256(val, tid, tid, cv, ck, l1v[g], l1k[g]);
    }
    // Level 2
    for (int G2 = 0; G2 < 2; ++G2) {
        int a = tid >> 4, b2 = tid & 15;
        int pe = l1k[2 * G2][a], po = l1k[2 * G2 + 1][b2];
        int ie = pe >> 4, io = pe & 15, je = po >> 4, jo = po & 15;
        int c0 = 4 * G2, c1 = 4 * G2 + 1, c2 = 4 * G2 + 2, c3 = 4 * G2 + 3;
        double cross = (double)Dsh[pidx(c0, c2) * 256 + ie * 16 + je]
                     + (double)Dsh[pidx(c0, c3) * 256 + ie * 16 + jo]
                     + (double)Dsh[pidx(c1, c2) * 256 + io * 16 + je]
                     + (double)Dsh[pidx(c1, c3) * 256 + io * 16 + jo];
        double val = l1v[2 * G2][a] + l1v[2 * G2 + 1][b2] - xes + 2.0 * cross;
        top16_256(val, tid, tid, cv, ck, tmpV, tmpK);
        if (tid < 16) {
            l2v[G2][tid] = tmpV[tid];
            int kk = tmpK[tid];
            l2k[G2][tid] = (l1k[2 * G2][kk >> 4] << 8) | l1k[2 * G2 + 1][kk & 15];
        }
        __syncthreads();
    }
    // Level 3: final merge + stable argmin
    {
        int a = tid >> 4, b2 = tid & 15;
        int p0 = l2k[0][a], p1 = l2k[1][b2];
        int se[4] = { (p0 >> 12) & 15, (p0 >> 8) & 15, (p0 >> 4) & 15, p0 & 15 };
        int so[4] = { (p1 >> 12) & 15, (p1 >> 8) & 15, (p1 >> 4) & 15, p1 & 15 };
        double cross = 0.0;
#pragma unroll
        for (int mm = 0; mm < 4; ++mm)
#pragma unroll
            for (int q = 0; q < 4; ++q)
                cross += (double)Dsh[pidx(mm, 4 + q) * 256 + se[mm] * 16 + so[q]];
        double val = l2v[0][a] + l2v[1][b2] - xes + 2.0 * cross;
        top16_256(val, tid, tid, cv, ck, tmpV, tmpK);
        if (tid == 0) {
            int k = tmpK[0];
            int a0 = k >> 4, b0 = k & 15;
            int p0w = l2k[0][a0], p1w = l2k[1][b0];
            int sl[8] = { (p0w >> 12) & 15, (p0w >> 8) & 15, (p0w >> 4) & 15, p0w & 15,
                          (p1w >> 12) & 15, (p1w >> 8) & 15, (p1w >> 4) & 15, p1w & 15 };
            for (int n = 0; n < NCBK; ++n) {
                int ci = tk[n][sl[n]];
                idx[b * NCBK + n] = ci;
                if (out) out[b * NCBK + n] = ci;
            }
        }
    }
}

extern "C" void kernel_launch(void* const* d_in, const int* in_sizes, int n_in,
                              void* d_out, int out_size, void* d_ws, size_t ws_size,
                              hipStream_t stream) {
    const float* x    = (const float*)d_in[0];  // (512, 256)
    const float* w    = (const float*)d_in[1];  // (2048, 256)
    const float* bias = (const float*)d_in[2];  // (2048,)
    const float* c    = (const float*)d_in[3];  // (2048, 256)
    int* out = (int*)d_out;                     // (512, 8) int32
    char* ws = (char*)d_ws;

    // workspace layout (~50 MB)
    double* G     = (double*)(ws);               // 2048*2048*8 = 33,554,432
    double* Xc    = (double*)(ws + 33554432);    // 512*2048*8 = 8,388,608
    double* Xw    = (double*)(ws + 41943040);    // 512*2048*8 = 8,388,608
    double* Gdiag = (double*)(ws + 50331648);    // 2048*8     = 16,384
    double* t16v  = (double*)(ws + 50348032);    // 512*8*16*8 = 524,288
    int*    t16k  = (int*)   (ws + 50872320);    // 512*8*16*4 = 262,144
    int*    idx   = (int*)   (ws + 51134464);    // 512*8*4    = 16,384
    double* xnorm = (double*)(ws + 51150848);    // 512*8      = 4,096

    k_gemm_nt<<<dim3(32, 8),  256, 0, stream>>>(x, w, Xw, W2);
    k_gemm_nt<<<dim3(32, 8),  256, 0, stream>>>(x, c, Xc, W2);
    k_gemm_nt<<<dim3(32, 32), 256, 0, stream>>>(c, c, G,  W2);
    k_gdiag<<<8, 256, 0, stream>>>(G, Gdiag);
    k_xnorm<<<NB, 64, 0, stream>>>(x, xnorm);
    k_argmax2<<<dim3(NCBK, NB), 256, 0, stream>>>(Xw, bias, idx);

    for (int it = 0; it < NITR; ++it) {
        k_cost3<<<dim3(NCBK, NB), 256, 0, stream>>>(G, Xc, Gdiag, xnorm, idx, t16v, t16k);
        k_tourney3<<<NB, 256, 0, stream>>>(G, Xc, xnorm, t16v, t16k, idx,
                                           (it == NITR - 1) ? out : nullptr);
    }
}

// Round 4
// 493.522 us; speedup vs baseline: 3.5279x; 1.1303x over previous
//
#include <hip/hip_runtime.h>
#include <math.h>

// Problem constants (from reference)
#define NB   512   // batch
#define DIMD 256   // dim
#define CBN  256   // codewords per codebook
#define NCBK 8     // codebooks
#define NITR 5     // refinement iterations
#define TOPK 16    // K_CUTOFF
#define W2   2048  // NCBK*CBN

// pair index for m<n among 8 codebooks (28 pairs)
__device__ __forceinline__ int pidx(int m, int n) {
    return m * 8 - (m * (m + 1)) / 2 + (n - m - 1);
}

__device__ const int PM28[28] = {0,0,0,0,0,0,0, 1,1,1,1,1,1, 2,2,2,2,2, 3,3,3,3, 4,4,4, 5,5, 6};
__device__ const int PN28[28] = {1,2,3,4,5,6,7, 2,3,4,5,6,7, 3,4,5,6,7, 4,5,6,7, 5,6,7, 6,7, 7};

__device__ __forceinline__ bool kgt(double v1, int k1, double v2, int k2) {
    return (v1 > v2) || (v1 == v2 && k1 > k2);
}

// Bitonic sort of 64 (v,k) pairs, one per lane, ascending by (v,k). No barriers.
__device__ __forceinline__ void wave_sort64(double& v, int& k, int lane) {
#pragma unroll
    for (int size = 2; size <= 64; size <<= 1) {
#pragma unroll
        for (int stride = size >> 1; stride > 0; stride >>= 1) {
            double pv = __shfl_xor(v, stride, 64);
            int pk = __shfl_xor(k, stride, 64);
            bool asc = ((lane & size) == 0);
            bool lower = (lane & stride) == 0;
            bool gt = kgt(v, k, pv, pk);
            bool take = asc ? (lower ? gt : !gt) : (lower ? !gt : gt);
            if (take) { v = pv; k = pk; }
        }
    }
}

// Stable top-16 of 256 (v,k) pairs (one per thread, 4 waves).
__device__ __forceinline__ void top16_256(double v, int k, int tid,
                                          double* cv, int* ck,
                                          double* outV, int* outK) {
    int lane = tid & 63, wave = tid >> 6;
    wave_sort64(v, k, lane);
    if (lane < 16) { cv[wave * 16 + lane] = v; ck[wave * 16 + lane] = k; }
    __syncthreads();
    if (wave == 0) {
        double mv = cv[lane]; int mk = ck[lane];
        wave_sort64(mv, mk, lane);
        if (lane < 16) { outV[lane] = mv; outK[lane] = mk; }
    }
    __syncthreads();
}

// ---- GEMM: Out[i][j] = sum_k A[i][k]*B[j][k], fp32 in, fp64 out, K=256 ----
__global__ __launch_bounds__(256) void k_gemm_nt(
        const float* __restrict__ A, const float* __restrict__ B,
        double* __restrict__ Out, int ldo) {
    __shared__ float As[64][17];
    __shared__ float Bs[64][17];
    int tid = threadIdx.x;
    int ty = tid >> 4, tx = tid & 15;
    int row0 = blockIdx.y * 64, col0 = blockIdx.x * 64;
    int lr = tid >> 2, lk = (tid & 3) * 4;
    double acc[4][4] = {};
    for (int k0 = 0; k0 < DIMD; k0 += 16) {
        float4 av = *(const float4*)(A + (size_t)(row0 + lr) * DIMD + k0 + lk);
        float4 bv = *(const float4*)(B + (size_t)(col0 + lr) * DIMD + k0 + lk);
        __syncthreads();
        As[lr][lk + 0] = av.x; As[lr][lk + 1] = av.y;
        As[lr][lk + 2] = av.z; As[lr][lk + 3] = av.w;
        Bs[lr][lk + 0] = bv.x; Bs[lr][lk + 1] = bv.y;
        Bs[lr][lk + 2] = bv.z; Bs[lr][lk + 3] = bv.w;
        __syncthreads();
#pragma unroll 4
        for (int kk = 0; kk < 16; ++kk) {
            double a[4], b[4];
#pragma unroll
            for (int i = 0; i < 4; ++i) a[i] = (double)As[4 * ty + i][kk];
#pragma unroll
            for (int j = 0; j < 4; ++j) b[j] = (double)Bs[4 * tx + j][kk];
#pragma unroll
            for (int i = 0; i < 4; ++i)
#pragma unroll
                for (int j = 0; j < 4; ++j) acc[i][j] = fma(a[i], b[j], acc[i][j]);
        }
    }
#pragma unroll
    for (int i = 0; i < 4; ++i)
#pragma unroll
        for (int j = 0; j < 4; ++j)
            Out[(size_t)(row0 + 4 * ty + i) * ldo + col0 + 4 * tx + j] = acc[i][j];
}

// ---- Symmetric Gram GEMM: G = C*C^T, upper-triangle blocks + LDS-transposed mirror ----
__global__ __launch_bounds__(256) void k_gemm_sym(
        const float* __restrict__ C, double* __restrict__ Out) {
    __shared__ float As[64][17];
    __shared__ float Bs[64][17];
    __shared__ double Tr[64][65];
    int tid = threadIdx.x;
    int ty = tid >> 4, tx = tid & 15;
    // decode linear block -> upper-triangle (bi, bj), bi <= bj, 32x32 tile grid
    int t = blockIdx.x, bi = 0;
    while (t >= 32 - bi) { t -= 32 - bi; ++bi; }
    int bj = bi + t;
    int row0 = bi * 64, col0 = bj * 64;
    int lr = tid >> 2, lk = (tid & 3) * 4;
    double acc[4][4] = {};
    for (int k0 = 0; k0 < DIMD; k0 += 16) {
        float4 av = *(const float4*)(C + (size_t)(row0 + lr) * DIMD + k0 + lk);
        float4 bv = *(const float4*)(C + (size_t)(col0 + lr) * DIMD + k0 + lk);
        __syncthreads();
        As[lr][lk + 0] = av.x; As[lr][lk + 1] = av.y;
        As[lr][lk + 2] = av.z; As[lr][lk + 3] = av.w;
        Bs[lr][lk + 0] = bv.x; Bs[lr][lk + 1] = bv.y;
        Bs[lr][lk + 2] = bv.z; Bs[lr][lk + 3] = bv.w;
        __syncthreads();
#pragma unroll 4
        for (int kk = 0; kk < 16; ++kk) {
            double a[4], b[4];
#pragma unroll
            for (int i = 0; i < 4; ++i) a[i] = (double)As[4 * ty + i][kk];
#pragma unroll
            for (int j = 0; j < 4; ++j) b[j] = (double)Bs[4 * tx + j][kk];
#pragma unroll
            for (int i = 0; i < 4; ++i)
#pragma unroll
                for (int j = 0; j < 4; ++j) acc[i][j] = fma(a[i], b[j], acc[i][j]);
        }
    }
#pragma unroll
    for (int i = 0; i < 4; ++i)
#pragma unroll
        for (int j = 0; j < 4; ++j)
            Out[(size_t)(row0 + 4 * ty + i) * W2 + col0 + 4 * tx + j] = acc[i][j];
    if (bi != bj) {
        __syncthreads();
#pragma unroll
        for (int i = 0; i < 4; ++i)
#pragma unroll
            for (int j = 0; j < 4; ++j)
                Tr[4 * tx + j][4 * ty + i] = acc[i][j];
        __syncthreads();
#pragma unroll
        for (int i = 0; i < 4; ++i)
#pragma unroll
            for (int j = 0; j < 4; ++j)
                Out[(size_t)(col0 + 4 * ty + i) * W2 + row0 + 4 * tx + j] = Tr[4 * ty + i][4 * tx + j];
    }
}

// ---- Gdiag[j] = G[j][j] ----
__global__ __launch_bounds__(256) void k_gdiag(const double* __restrict__ G,
                                               double* __restrict__ Gdiag) {
    int j = blockIdx.x * 256 + threadIdx.x;
    Gdiag[j] = G[(size_t)j * W2 + j];
}

// ---- xnorm[b] = ||x_b||^2 (fp64), one wave per row ----
__global__ __launch_bounds__(64) void k_xnorm(const float* __restrict__ x,
                                              double* __restrict__ xn) {
    int b = blockIdx.x, lane = threadIdx.x;
    float4 v = *(const float4*)(x + (size_t)b * DIMD + lane * 4);
    double s = (double)v.x * v.x + (double)v.y * v.y
             + (double)v.z * v.z + (double)v.w * v.w;
#pragma unroll
    for (int st = 32; st > 0; st >>= 1) s += __shfl_down(s, st, 64);
    if (lane == 0) xn[b] = s;
}

// ---- initial argmax from Xw + bias; also zeroes conv flags ----
__global__ __launch_bounds__(256) void k_argmax2(
        const double* __restrict__ Xw, const float* __restrict__ bias,
        int* __restrict__ idx, int* __restrict__ conv) {
    int n = blockIdx.x, b = blockIdx.y, j = threadIdx.x;
    __shared__ double sv[256];
    __shared__ int sk[256];
    sv[j] = Xw[(size_t)b * W2 + n * CBN + j] + (double)bias[n * CBN + j];
    sk[j] = j;
    __syncthreads();
    for (int s = 128; s > 0; s >>= 1) {
        if (j < s) {
            if (sv[j + s] > sv[j] || (sv[j + s] == sv[j] && sk[j + s] < sk[j])) {
                sv[j] = sv[j + s]; sk[j] = sk[j + s];
            }
        }
        __syncthreads();
    }
    if (j == 0) {
        idx[b * NCBK + n] = sk[0];
        if (n == 0) conv[b] = 0;
    }
}

// ---- fully fused refinement iteration: costs + top16 x8 + D-tiles + tournament ----
__global__ __launch_bounds__(256) void k_iter(
        const double* __restrict__ G, const double* __restrict__ Xc,
        const double* __restrict__ Gdiag, const double* __restrict__ xnorm,
        int* __restrict__ idx, int* __restrict__ conv, int* __restrict__ out) {
    int b = blockIdx.x, tid = threadIdx.x;
    __shared__ float Dsh[28 * 256];          // 28 KB
    __shared__ double Ecr[NCBK * NCBK * 16]; // 8 KB
    __shared__ int jm[NCBK];
    __shared__ double gmat[64], Xcj[NCBK], Sj[NCBK], jdiag[NCBK];
    __shared__ double xes_sh;
    __shared__ double tv[NCBK][16];
    __shared__ int tk[NCBK][16];
    __shared__ int amr[NCBK][16];
    __shared__ double l1v[4][16]; __shared__ int l1k[4][16];
    __shared__ double l2v[2][16]; __shared__ int l2k[2][16];
    __shared__ double cv[64]; __shared__ int ck[64];
    __shared__ double tmpV[16]; __shared__ int tmpK[16];

    if (conv[b]) {  // converged: iteration is the identity; only emit output if final
        if (out && tid < NCBK) out[b * NCBK + tid] = idx[b * NCBK + tid];
        return;
    }
    if (tid < NCBK) jm[tid] = tid * CBN + idx[b * NCBK + tid];
    __syncthreads();
    if (tid < 64) gmat[tid] = G[(size_t)jm[tid >> 3] * W2 + jm[tid & 7]];
    else if (tid < 72) Xcj[tid - 64] = Xc[(size_t)b * W2 + jm[tid - 64]];
    else if (tid < 80) jdiag[tid - 72] = Gdiag[jm[tid - 72]];
    __syncthreads();
    if (tid < NCBK) {
        double s = 0.0;
        for (int mp = 0; mp < NCBK; ++mp) s += gmat[mp * 8 + tid];
        Sj[tid] = s - Xcj[tid];
    }
    __syncthreads();
    if (tid == 0) {
        double e = xnorm[b];
        for (int m = 0; m < NCBK; ++m) e += Sj[m] - Xcj[m];
        xes_sh = e;
    }
    __syncthreads();

    // ---- cost phase: per codebook n, 256 candidate costs + stable top-16 ----
    for (int n = 0; n < NCBK; ++n) {
        int kp = n * CBN + tid;
        double s = -Xc[(size_t)b * W2 + kp];
        double gjn = 0.0;
#pragma unroll
        for (int m = 0; m < NCBK; ++m) {
            double g = G[(size_t)jm[m] * W2 + kp];
            s += g;
            if (m == n) gjn = g;
        }
        double cost = (xes_sh - 2.0 * Sj[n] + jdiag[n]) + 2.0 * (s - gjn) + Gdiag[kp];
        top16_256(cost, tid, tid, cv, ck, tv[n], tk[n]);
    }
    if (tid < 128) { int m = tid >> 4, i = tid & 15; amr[m][i] = m * CBN + tk[m][i]; }
    __syncthreads();

    // ---- D-tiles in LDS ----
    for (int t = tid; t < NCBK * NCBK * 16; t += 256) {
        int m = t >> 7, nn = (t >> 4) & 7, ii = t & 15;
        Ecr[t] = G[(size_t)amr[m][ii] * W2 + jm[nn]];
    }
    __syncthreads();
    {
        int i = tid >> 4, j = tid & 15;
        for (int p = 0; p < 28; ++p) {
            int m = PM28[p], n = PN28[p];
            double v = G[(size_t)amr[m][i] * W2 + amr[n][j]]
                     - Ecr[m * 128 + n * 16 + i]
                     - Ecr[n * 128 + m * 16 + j]
                     + gmat[m * 8 + n];
            Dsh[p * 256 + tid] = (float)v;
        }
    }
    __syncthreads();
    double xes = xes_sh;

    // ---- tournament ----
    for (int g = 0; g < 4; ++g) {
        int i = tid >> 4, j = tid & 15;
        double val = tv[2 * g][i] + tv[2 * g + 1][j] - xes
                   + 2.0 * (double)Dsh[pidx(2 * g, 2 * g + 1) * 256 + tid];
        top16_256(val, tid, tid, cv, ck, l1v[g], l1k[g]);
    }
    for (int G2 = 0; G2 < 2; ++G2) {
        int a = tid >> 4, b2 = tid & 15;
        int pe = l1k[2 * G2][a], po = l1k[2 * G2 + 1][b2];
        int ie = pe >> 4, io = pe & 15, je = po >> 4, jo = po & 15;
        int c0 = 4 * G2, c1 = 4 * G2 + 1, c2 = 4 * G2 + 2, c3 = 4 * G2 + 3;
        double cross = (double)Dsh[pidx(c0, c2) * 256 + ie * 16 + je]
                     + (double)Dsh[pidx(c0, c3) * 256 + ie * 16 + jo]
                     + (double)Dsh[pidx(c1, c2) * 256 + io * 16 + je]
                     + (double)Dsh[pidx(c1, c3) * 256 + io * 16 + jo];
        double val = l1v[2 * G2][a] + l1v[2 * G2 + 1][b2] - xes + 2.0 * cross;
        top16_256(val, tid, tid, cv, ck, tmpV, tmpK);
        if (tid < 16) {
            l2v[G2][tid] = tmpV[tid];
            int kk = tmpK[tid];
            l2k[G2][tid] = (l1k[2 * G2][kk >> 4] << 8) | l1k[2 * G2 + 1][kk & 15];
        }
        __syncthreads();
    }
    {
        int a = tid >> 4, b2 = tid & 15;
        int p0 = l2k[0][a], p1 = l2k[1][b2];
        int se[4] = { (p0 >> 12) & 15, (p0 >> 8) & 15, (p0 >> 4) & 15, p0 & 15 };
        int so[4] = { (p1 >> 12) & 15, (p1 >> 8) & 15, (p1 >> 4) & 15, p1 & 15 };
        double cross = 0.0;
#pragma unroll
        for (int mm = 0; mm < 4; ++mm)
#pragma unroll
            for (int q = 0; q < 4; ++q)
                cross += (double)Dsh[pidx(mm, 4 + q) * 256 + se[mm] * 16 + so[q]];
        double val = l2v[0][a] + l2v[1][b2] - xes + 2.0 * cross;
        top16_256(val, tid, tid, cv, ck, tmpV, tmpK);
        if (tid == 0) {
            int k = tmpK[0];
            int a0 = k >> 4, b0 = k & 15;
            int p0w = l2k[0][a0], p1w = l2k[1][b0];
            int sl[8] = { (p0w >> 12) & 15, (p0w >> 8) & 15, (p0w >> 4) & 15, p0w & 15,
                          (p1w >> 12) & 15, (p1w >> 8) & 15, (p1w >> 4) & 15, p1w & 15 };
            int changed = 0;
            for (int n = 0; n < NCBK; ++n) {
                int ci = tk[n][sl[n]];
                if (ci != jm[n] - n * CBN) changed = 1;
                idx[b * NCBK + n] = ci;
                if (out) out[b * NCBK + n] = ci;
            }
            conv[b] = changed ? 0 : 1;
        }
    }
}

extern "C" void kernel_launch(void* const* d_in, const int* in_sizes, int n_in,
                              void* d_out, int out_size, void* d_ws, size_t ws_size,
                              hipStream_t stream) {
    const float* x    = (const float*)d_in[0];  // (512, 256)
    const float* w    = (const float*)d_in[1];  // (2048, 256)
    const float* bias = (const float*)d_in[2];  // (2048,)
    const float* c    = (const float*)d_in[3];  // (2048, 256)
    int* out = (int*)d_out;                     // (512, 8) int32
    char* ws = (char*)d_ws;

    // workspace layout (~50.5 MB)
    double* G     = (double*)(ws);               // 2048*2048*8 = 33,554,432
    double* Xc    = (double*)(ws + 33554432);    // 512*2048*8 = 8,388,608
    double* Xw    = (double*)(ws + 41943040);    // 512*2048*8 = 8,388,608
    double* Gdiag = (double*)(ws + 50331648);    // 2048*8     = 16,384
    int*    idx   = (int*)   (ws + 50348032);    // 512*8*4    = 16,384
    double* xnorm = (double*)(ws + 50364416);    // 512*8      = 4,096
    int*    conv  = (int*)   (ws + 50368512);    // 512*4      = 2,048

    k_gemm_nt<<<dim3(32, 8), 256, 0, stream>>>(x, w, Xw, W2);
    k_gemm_nt<<<dim3(32, 8), 256, 0, stream>>>(x, c, Xc, W2);
    k_gemm_sym<<<528, 256, 0, stream>>>(c, G);
    k_gdiag<<<8, 256, 0, stream>>>(G, Gdiag);
    k_xnorm<<<NB, 64, 0, stream>>>(x, xnorm);
    k_argmax2<<<dim3(NCBK, NB), 256, 0, stream>>>(Xw, bias, idx, conv);

    for (int it = 0; it < NITR; ++it) {
        k_iter<<<NB, 256, 0, stream>>>(G, Xc, Gdiag, xnorm, idx, conv,
                                       (it == NITR - 1) ? out : nullptr);
    }
}

// Round 5
// 463.092 us; speedup vs baseline: 3.7597x; 1.0657x over previous
//
#include <hip/hip_runtime.h>
#include <math.h>

// Problem constants (from reference)
#define NB   512   // batch
#define DIMD 256   // dim
#define CBN  256   // codewords per codebook
#define NCBK 8     // codebooks
#define NITR 5     // refinement iterations
#define TOPK 16    // K_CUTOFF
#define W2   2048  // NCBK*CBN

// pair index for m<n among 8 codebooks (28 pairs)
__device__ __forceinline__ int pidx(int m, int n) {
    return m * 8 - (m * (m + 1)) / 2 + (n - m - 1);
}

__device__ const int PM28[28] = {0,0,0,0,0,0,0, 1,1,1,1,1,1, 2,2,2,2,2, 3,3,3,3, 4,4,4, 5,5, 6};
__device__ const int PN28[28] = {1,2,3,4,5,6,7, 2,3,4,5,6,7, 3,4,5,6,7, 4,5,6,7, 5,6,7, 6,7, 7};

__device__ __forceinline__ bool kgt(double v1, int k1, double v2, int k2) {
    return (v1 > v2) || (v1 == v2 && k1 > k2);
}

// Bitonic sort of 64 (v,k) pairs, one per lane, ascending by (v,k). No barriers.
__device__ __forceinline__ void wave_sort64(double& v, int& k, int lane) {
#pragma unroll
    for (int size = 2; size <= 64; size <<= 1) {
#pragma unroll
        for (int stride = size >> 1; stride > 0; stride >>= 1) {
            double pv = __shfl_xor(v, stride, 64);
            int pk = __shfl_xor(k, stride, 64);
            bool asc = ((lane & size) == 0);
            bool lower = (lane & stride) == 0;
            bool gt = kgt(v, k, pv, pk);
            bool take = asc ? (lower ? gt : !gt) : (lower ? !gt : gt);
            if (take) { v = pv; k = pk; }
        }
    }
}

// Stable top-16 of 256 (v,k) pairs (one per thread, 4 waves).
__device__ __forceinline__ void top16_256(double v, int k, int tid,
                                          double* cv, int* ck,
                                          double* outV, int* outK) {
    int lane = tid & 63, wave = tid >> 6;
    wave_sort64(v, k, lane);
    if (lane < 16) { cv[wave * 16 + lane] = v; ck[wave * 16 + lane] = k; }
    __syncthreads();
    if (wave == 0) {
        double mv = cv[lane]; int mk = ck[lane];
        wave_sort64(mv, mk, lane);
        if (lane < 16) { outV[lane] = mv; outK[lane] = mk; }
    }
    __syncthreads();
}

// ---- GEMM: Out[i][j] = sum_k A[i][k]*B[j][k]; fp32 in, fp64 accum, fp32 out ----
__global__ __launch_bounds__(256) void k_gemm_nt(
        const float* __restrict__ A, const float* __restrict__ B,
        float* __restrict__ Out, int ldo) {
    __shared__ float As[64][17];
    __shared__ float Bs[64][17];
    int tid = threadIdx.x;
    int ty = tid >> 4, tx = tid & 15;
    int row0 = blockIdx.y * 64, col0 = blockIdx.x * 64;
    int lr = tid >> 2, lk = (tid & 3) * 4;
    double acc[4][4] = {};
    for (int k0 = 0; k0 < DIMD; k0 += 16) {
        float4 av = *(const float4*)(A + (size_t)(row0 + lr) * DIMD + k0 + lk);
        float4 bv = *(const float4*)(B + (size_t)(col0 + lr) * DIMD + k0 + lk);
        __syncthreads();
        As[lr][lk + 0] = av.x; As[lr][lk + 1] = av.y;
        As[lr][lk + 2] = av.z; As[lr][lk + 3] = av.w;
        Bs[lr][lk + 0] = bv.x; Bs[lr][lk + 1] = bv.y;
        Bs[lr][lk + 2] = bv.z; Bs[lr][lk + 3] = bv.w;
        __syncthreads();
#pragma unroll 4
        for (int kk = 0; kk < 16; ++kk) {
            double a[4], b[4];
#pragma unroll
            for (int i = 0; i < 4; ++i) a[i] = (double)As[4 * ty + i][kk];
#pragma unroll
            for (int j = 0; j < 4; ++j) b[j] = (double)Bs[4 * tx + j][kk];
#pragma unroll
            for (int i = 0; i < 4; ++i)
#pragma unroll
                for (int j = 0; j < 4; ++j) acc[i][j] = fma(a[i], b[j], acc[i][j]);
        }
    }
#pragma unroll
    for (int i = 0; i < 4; ++i)
#pragma unroll
        for (int j = 0; j < 4; ++j)
            Out[(size_t)(row0 + 4 * ty + i) * ldo + col0 + 4 * tx + j] = (float)acc[i][j];
}

// ---- Symmetric Gram GEMM: G = C*C^T, upper-triangle blocks + LDS-transposed mirror ----
__global__ __launch_bounds__(256) void k_gemm_sym(
        const float* __restrict__ C, float* __restrict__ Out) {
    __shared__ float As[64][17];
    __shared__ float Bs[64][17];
    __shared__ float Tr[64][65];
    int tid = threadIdx.x;
    int ty = tid >> 4, tx = tid & 15;
    int t = blockIdx.x, bi = 0;
    while (t >= 32 - bi) { t -= 32 - bi; ++bi; }
    int bj = bi + t;
    int row0 = bi * 64, col0 = bj * 64;
    int lr = tid >> 2, lk = (tid & 3) * 4;
    double acc[4][4] = {};
    for (int k0 = 0; k0 < DIMD; k0 += 16) {
        float4 av = *(const float4*)(C + (size_t)(row0 + lr) * DIMD + k0 + lk);
        float4 bv = *(const float4*)(C + (size_t)(col0 + lr) * DIMD + k0 + lk);
        __syncthreads();
        As[lr][lk + 0] = av.x; As[lr][lk + 1] = av.y;
        As[lr][lk + 2] = av.z; As[lr][lk + 3] = av.w;
        Bs[lr][lk + 0] = bv.x; Bs[lr][lk + 1] = bv.y;
        Bs[lr][lk + 2] = bv.z; Bs[lr][lk + 3] = bv.w;
        __syncthreads();
#pragma unroll 4
        for (int kk = 0; kk < 16; ++kk) {
            double a[4], b[4];
#pragma unroll
            for (int i = 0; i < 4; ++i) a[i] = (double)As[4 * ty + i][kk];
#pragma unroll
            for (int j = 0; j < 4; ++j) b[j] = (double)Bs[4 * tx + j][kk];
#pragma unroll
            for (int i = 0; i < 4; ++i)
#pragma unroll
                for (int j = 0; j < 4; ++j) acc[i][j] = fma(a[i], b[j], acc[i][j]);
        }
    }
#pragma unroll
    for (int i = 0; i < 4; ++i)
#pragma unroll
        for (int j = 0; j < 4; ++j)
            Out[(size_t)(row0 + 4 * ty + i) * W2 + col0 + 4 * tx + j] = (float)acc[i][j];
    if (bi != bj) {
        __syncthreads();
#pragma unroll
        for (int i = 0; i < 4; ++i)
#pragma unroll
            for (int j = 0; j < 4; ++j)
                Tr[4 * tx + j][4 * ty + i] = (float)acc[i][j];
        __syncthreads();
#pragma unroll
        for (int i = 0; i < 4; ++i)
#pragma unroll
            for (int j = 0; j < 4; ++j)
                Out[(size_t)(col0 + 4 * ty + i) * W2 + row0 + 4 * tx + j] = Tr[4 * ty + i][4 * tx + j];
    }
}

// ---- Gdiag[j] = G[j][j] ----
__global__ __launch_bounds__(256) void k_gdiag(const float* __restrict__ G,
                                               float* __restrict__ Gdiag) {
    int j = blockIdx.x * 256 + threadIdx.x;
    Gdiag[j] = G[(size_t)j * W2 + j];
}

// ---- xnorm[b] = ||x_b||^2 (fp64), one wave per row ----
__global__ __launch_bounds__(64) void k_xnorm(const float* __restrict__ x,
                                              double* __restrict__ xn) {
    int b = blockIdx.x, lane = threadIdx.x;
    float4 v = *(const float4*)(x + (size_t)b * DIMD + lane * 4);
    double s = (double)v.x * v.x + (double)v.y * v.y
             + (double)v.z * v.z + (double)v.w * v.w;
#pragma unroll
    for (int st = 32; st > 0; st >>= 1) s += __shfl_down(s, st, 64);
    if (lane == 0) xn[b] = s;
}

// ---- initial argmax from Xw + bias; also zeroes conv flags ----
__global__ __launch_bounds__(256) void k_argmax2(
        const float* __restrict__ Xw, const float* __restrict__ bias,
        int* __restrict__ idx, int* __restrict__ conv) {
    int n = blockIdx.x, b = blockIdx.y, j = threadIdx.x;
    __shared__ double sv[256];
    __shared__ int sk[256];
    sv[j] = (double)Xw[(size_t)b * W2 + n * CBN + j] + (double)bias[n * CBN + j];
    sk[j] = j;
    __syncthreads();
    for (int s = 128; s > 0; s >>= 1) {
        if (j < s) {
            if (sv[j + s] > sv[j] || (sv[j + s] == sv[j] && sk[j + s] < sk[j])) {
                sv[j] = sv[j + s]; sk[j] = sk[j + s];
            }
        }
        __syncthreads();
    }
    if (j == 0) {
        idx[b * NCBK + n] = sk[0];
        if (n == 0) conv[b] = 0;
    }
}

// ---- fully fused refinement iteration: costs + top16 x8 + D-tiles + tournament ----
__global__ __launch_bounds__(256) void k_iter(
        const float* __restrict__ G, const float* __restrict__ Xc,
        const float* __restrict__ Gdiag, const double* __restrict__ xnorm,
        int* __restrict__ idx, int* __restrict__ conv, int* __restrict__ out) {
    int b = blockIdx.x, tid = threadIdx.x;
    __shared__ float Dsh[28 * 256];          // 28 KB
    __shared__ float Ecr[NCBK * NCBK * 16];  // 4 KB
    __shared__ int jm[NCBK];
    __shared__ double gmat[64], Xcj[NCBK], Sj[NCBK], jdiag[NCBK];
    __shared__ double xes_sh;
    __shared__ double tv[NCBK][16];
    __shared__ int tk[NCBK][16];
    __shared__ int amr[NCBK][16];
    __shared__ double l1v[4][16]; __shared__ int l1k[4][16];
    __shared__ double l2v[2][16]; __shared__ int l2k[2][16];
    __shared__ double cv[64]; __shared__ int ck[64];
    __shared__ double tmpV[16]; __shared__ int tmpK[16];

    if (conv[b]) {  // converged: iteration is the identity; only emit output if final
        if (out && tid < NCBK) out[b * NCBK + tid] = idx[b * NCBK + tid];
        return;
    }
    if (tid < NCBK) jm[tid] = tid * CBN + idx[b * NCBK + tid];
    __syncthreads();
    if (tid < 64) gmat[tid] = (double)G[(size_t)jm[tid >> 3] * W2 + jm[tid & 7]];
    else if (tid < 72) Xcj[tid - 64] = (double)Xc[(size_t)b * W2 + jm[tid - 64]];
    else if (tid < 80) jdiag[tid - 72] = (double)Gdiag[jm[tid - 72]];
    __syncthreads();
    if (tid < NCBK) {
        double s = 0.0;
        for (int mp = 0; mp < NCBK; ++mp) s += gmat[mp * 8 + tid];
        Sj[tid] = s - Xcj[tid];
    }
    __syncthreads();
    if (tid == 0) {
        double e = xnorm[b];
        for (int m = 0; m < NCBK; ++m) e += Sj[m] - Xcj[m];
        xes_sh = e;
    }
    __syncthreads();

    // ---- cost phase: per codebook n, 256 candidate costs + stable top-16 ----
    for (int n = 0; n < NCBK; ++n) {
        int kp = n * CBN + tid;
        double s = -(double)Xc[(size_t)b * W2 + kp];
        double gjn = 0.0;
#pragma unroll
        for (int m = 0; m < NCBK; ++m) {
            double g = (double)G[(size_t)jm[m] * W2 + kp];
            s += g;
            if (m == n) gjn = g;
        }
        double cost = (xes_sh - 2.0 * Sj[n] + jdiag[n]) + 2.0 * (s - gjn) + (double)Gdiag[kp];
        top16_256(cost, tid, tid, cv, ck, tv[n], tk[n]);
    }
    if (tid < 128) { int m = tid >> 4, i = tid & 15; amr[m][i] = m * CBN + tk[m][i]; }
    __syncthreads();

    // ---- D-tiles in LDS ----
    for (int t = tid; t < NCBK * NCBK * 16; t += 256) {
        int m = t >> 7, nn = (t >> 4) & 7, ii = t & 15;
        Ecr[t] = G[(size_t)amr[m][ii] * W2 + jm[nn]];
    }
    __syncthreads();
    {
        int i = tid >> 4, j = tid & 15;
        for (int p = 0; p < 28; ++p) {
            int m = PM28[p], n = PN28[p];
            double v = (double)G[(size_t)amr[m][i] * W2 + amr[n][j]]
                     - (double)Ecr[m * 128 + n * 16 + i]
                     - (double)Ecr[n * 128 + m * 16 + j]
                     + gmat[m * 8 + n];
            Dsh[p * 256 + tid] = (float)v;
        }
    }
    __syncthreads();
    double xes = xes_sh;

    // ---- tournament ----
    for (int g = 0; g < 4; ++g) {
        int i = tid >> 4, j = tid & 15;
        double val = tv[2 * g][i] + tv[2 * g + 1][j] - xes
                   + 2.0 * (double)Dsh[pidx(2 * g, 2 * g + 1) * 256 + tid];
        top16_256(val, tid, tid, cv, ck, l1v[g], l1k[g]);
    }
    for (int G2 = 0; G2 < 2; ++G2) {
        int a = tid >> 4, b2 = tid & 15;
        int pe = l1k[2 * G2][a], po = l1k[2 * G2 + 1][b2];
        int ie = pe >> 4, io = pe & 15, je = po >> 4, jo = po & 15;
        int c0 = 4 * G2, c1 = 4 * G2 + 1, c2 = 4 * G2 + 2, c3 = 4 * G2 + 3;
        double cross = (double)Dsh[pidx(c0, c2) * 256 + ie * 16 + je]
                     + (double)Dsh[pidx(c0, c3) * 256 + ie * 16 + jo]
                     + (double)Dsh[pidx(c1, c2) * 256 + io * 16 + je]
                     + (double)Dsh[pidx(c1, c3) * 256 + io * 16 + jo];
        double val = l1v[2 * G2][a] + l1v[2 * G2 + 1][b2] - xes + 2.0 * cross;
        top16_256(val, tid, tid, cv, ck, tmpV, tmpK);
        if (tid < 16) {
            l2v[G2][tid] = tmpV[tid];
            int kk = tmpK[tid];
            l2k[G2][tid] = (l1k[2 * G2][kk >> 4] << 8) | l1k[2 * G2 + 1][kk & 15];
        }
        __syncthreads();
    }
    {
        int a = tid >> 4, b2 = tid & 15;
        int p0 = l2k[0][a], p1 = l2k[1][b2];
        int se[4] = { (p0 >> 12) & 15, (p0 >> 8) & 15, (p0 >> 4) & 15, p0 & 15 };
        int so[4] = { (p1 >> 12) & 15, (p1 >> 8) & 15, (p1 >> 4) & 15, p1 & 15 };
        double cross = 0.0;
#pragma unroll
        for (int mm = 0; mm < 4; ++mm)
#pragma unroll
            for (int q = 0; q < 4; ++q)
                cross += (double)Dsh[pidx(mm, 4 + q) * 256 + se[mm] * 16 + so[q]];
        double val = l2v[0][a] + l2v[1][b2] - xes + 2.0 * cross;
        top16_256(val, tid, tid, cv, ck, tmpV, tmpK);
        if (tid == 0) {
            int k = tmpK[0];
            int a0 = k >> 4, b0 = k & 15;
            int p0w = l2k[0][a0], p1w = l2k[1][b0];
            int sl[8] = { (p0w >> 12) & 15, (p0w >> 8) & 15, (p0w >> 4) & 15, p0w & 15,
                          (p1w >> 12) & 15, (p1w >> 8) & 15, (p1w >> 4) & 15, p1w & 15 };
            int changed = 0;
            for (int n = 0; n < NCBK; ++n) {
                int ci = tk[n][sl[n]];
                if (ci != jm[n] - n * CBN) changed = 1;
                idx[b * NCBK + n] = ci;
                if (out) out[b * NCBK + n] = ci;
            }
            conv[b] = changed ? 0 : 1;
        }
    }
}

extern "C" void kernel_launch(void* const* d_in, const int* in_sizes, int n_in,
                              void* d_out, int out_size, void* d_ws, size_t ws_size,
                              hipStream_t stream) {
    const float* x    = (const float*)d_in[0];  // (512, 256)
    const float* w    = (const float*)d_in[1];  // (2048, 256)
    const float* bias = (const float*)d_in[2];  // (2048,)
    const float* c    = (const float*)d_in[3];  // (2048, 256)
    int* out = (int*)d_out;                     // (512, 8) int32
    char* ws = (char*)d_ws;

    // workspace layout (~25.2 MB, fp32 tables)
    float*  G     = (float*) (ws);               // 2048*2048*4 = 16,777,216
    float*  Xc    = (float*) (ws + 16777216);    // 512*2048*4 = 4,194,304
    float*  Xw    = (float*) (ws + 20971520);    // 512*2048*4 = 4,194,304
    float*  Gdiag = (float*) (ws + 25165824);    // 2048*4     = 8,192
    int*    idx   = (int*)   (ws + 25174016);    // 512*8*4    = 16,384
    double* xnorm = (double*)(ws + 25190400);    // 512*8      = 4,096
    int*    conv  = (int*)   (ws + 25194496);    // 512*4      = 2,048

    k_gemm_nt<<<dim3(32, 8), 256, 0, stream>>>(x, w, Xw, W2);
    k_gemm_nt<<<dim3(32, 8), 256, 0, stream>>>(x, c, Xc, W2);
    k_gemm_sym<<<528, 256, 0, stream>>>(c, G);
    k_gdiag<<<8, 256, 0, stream>>>(G, Gdiag);
    k_xnorm<<<NB, 64, 0, stream>>>(x, xnorm);
    k_argmax2<<<dim3(NCBK, NB), 256, 0, stream>>>(Xw, bias, idx, conv);

    for (int it = 0; it < NITR; ++it) {
        k_iter<<<NB, 256, 0, stream>>>(G, Xc, Gdiag, xnorm, idx, conv,
                                       (it == NITR - 1) ? out : nullptr);
    }
}

// Round 7
// 416.150 us; speedup vs baseline: 4.1838x; 1.1128x over previous
//
#include <hip/hip_runtime.h>
#include <math.h>

// Problem constants (from reference)
#define NB   512   // batch
#define DIMD 256   // dim
#define CBN  256   // codewords per codebook
#define NCBK 8     // codebooks
#define NITR 5     // refinement iterations
#define TOPK 16    // K_CUTOFF
#define W2   2048  // NCBK*CBN

// pair index for m<n among 8 codebooks (28 pairs)
__device__ __forceinline__ int pidx(int m, int n) {
    return m * 8 - (m * (m + 1)) / 2 + (n - m - 1);
}

__device__ const int PM28[28] = {0,0,0,0,0,0,0, 1,1,1,1,1,1, 2,2,2,2,2, 3,3,3,3, 4,4,4, 5,5, 6};
__device__ const int PN28[28] = {1,2,3,4,5,6,7, 2,3,4,5,6,7, 3,4,5,6,7, 4,5,6,7, 5,6,7, 6,7, 7};

__device__ __forceinline__ bool kgt(double v1, int k1, double v2, int k2) {
    return (v1 > v2) || (v1 == v2 && k1 > k2);
}

// Bitonic sort of 64 (v,k) pairs, one per lane, ascending by (v,k). No barriers.
__device__ __forceinline__ void wave_sort64(double& v, int& k, int lane) {
#pragma unroll
    for (int size = 2; size <= 64; size <<= 1) {
#pragma unroll
        for (int stride = size >> 1; stride > 0; stride >>= 1) {
            double pv = __shfl_xor(v, stride, 64);
            int pk = __shfl_xor(k, stride, 64);
            bool asc = ((lane & size) == 0);
            bool lower = (lane & stride) == 0;
            bool gt = kgt(v, k, pv, pk);
            bool take = asc ? (lower ? gt : !gt) : (lower ? !gt : gt);
            if (take) { v = pv; k = pk; }
        }
    }
}

// Stable top-16 of 256 (v,k) pairs (one per thread, 4 waves).
__device__ __forceinline__ void top16_256(double v, int k, int tid,
                                          double* cv, int* ck,
                                          double* outV, int* outK) {
    int lane = tid & 63, wave = tid >> 6;
    wave_sort64(v, k, lane);
    if (lane < 16) { cv[wave * 16 + lane] = v; ck[wave * 16 + lane] = k; }
    __syncthreads();
    if (wave == 0) {
        double mv = cv[lane]; int mk = ck[lane];
        wave_sort64(mv, mk, lane);
        if (lane < 16) { outV[lane] = mv; outK[lane] = mk; }
    }
    __syncthreads();
}

// Stable argmin of 256 (v,k): lexicographic min. Result in outK[0] (and outV[0]).
__device__ __forceinline__ void argmin_256(double v, int k, int tid,
                                           double* cv, int* ck,
                                           double* outV, int* outK) {
    int lane = tid & 63, wave = tid >> 6;
#pragma unroll
    for (int st = 32; st > 0; st >>= 1) {
        double pv = __shfl_xor(v, st, 64);
        int pk = __shfl_xor(k, st, 64);
        if (kgt(v, k, pv, pk)) { v = pv; k = pk; }
    }
    if (lane == 0) { cv[wave] = v; ck[wave] = k; }
    __syncthreads();
    if (tid == 0) {
        double bv = cv[0]; int bk = ck[0];
        for (int w = 1; w < 4; ++w)
            if (kgt(bv, bk, cv[w], ck[w])) { bv = cv[w]; bk = ck[w]; }
        outV[0] = bv; outK[0] = bk;
    }
    __syncthreads();
}

// ---- GEMM: Out[i][j] = sum_k A[i][k]*B[j][k]; fp32 in, fp64 accum, fp32 out ----
__global__ __launch_bounds__(256) void k_gemm_nt(
        const float* __restrict__ A, const float* __restrict__ B,
        float* __restrict__ Out, int ldo) {
    __shared__ float As[64][17];
    __shared__ float Bs[64][17];
    int tid = threadIdx.x;
    int ty = tid >> 4, tx = tid & 15;
    int row0 = blockIdx.y * 64, col0 = blockIdx.x * 64;
    int lr = tid >> 2, lk = (tid & 3) * 4;
    double acc[4][4] = {};
    for (int k0 = 0; k0 < DIMD; k0 += 16) {
        float4 av = *(const float4*)(A + (size_t)(row0 + lr) * DIMD + k0 + lk);
        float4 bv = *(const float4*)(B + (size_t)(col0 + lr) * DIMD + k0 + lk);
        __syncthreads();
        As[lr][lk + 0] = av.x; As[lr][lk + 1] = av.y;
        As[lr][lk + 2] = av.z; As[lr][lk + 3] = av.w;
        Bs[lr][lk + 0] = bv.x; Bs[lr][lk + 1] = bv.y;
        Bs[lr][lk + 2] = bv.z; Bs[lr][lk + 3] = bv.w;
        __syncthreads();
#pragma unroll 4
        for (int kk = 0; kk < 16; ++kk) {
            double a[4], b[4];
#pragma unroll
            for (int i = 0; i < 4; ++i) a[i] = (double)As[4 * ty + i][kk];
#pragma unroll
            for (int j = 0; j < 4; ++j) b[j] = (double)Bs[4 * tx + j][kk];
#pragma unroll
            for (int i = 0; i < 4; ++i)
#pragma unroll
                for (int j = 0; j < 4; ++j) acc[i][j] = fma(a[i], b[j], acc[i][j]);
        }
    }
#pragma unroll
    for (int i = 0; i < 4; ++i)
#pragma unroll
        for (int j = 0; j < 4; ++j)
            Out[(size_t)(row0 + 4 * ty + i) * ldo + col0 + 4 * tx + j] = (float)acc[i][j];
}

// ---- Symmetric Gram GEMM: G = C*C^T, upper-triangle blocks + LDS-transposed mirror ----
__global__ __launch_bounds__(256) void k_gemm_sym(
        const float* __restrict__ C, float* __restrict__ Out) {
    __shared__ float As[64][17];
    __shared__ float Bs[64][17];
    __shared__ float Tr[64][65];
    int tid = threadIdx.x;
    int ty = tid >> 4, tx = tid & 15;
    int t = blockIdx.x, bi = 0;
    while (t >= 32 - bi) { t -= 32 - bi; ++bi; }
    int bj = bi + t;
    int row0 = bi * 64, col0 = bj * 64;
    int lr = tid >> 2, lk = (tid & 3) * 4;
    double acc[4][4] = {};
    for (int k0 = 0; k0 < DIMD; k0 += 16) {
        float4 av = *(const float4*)(C + (size_t)(row0 + lr) * DIMD + k0 + lk);
        float4 bv = *(const float4*)(C + (size_t)(col0 + lr) * DIMD + k0 + lk);
        __syncthreads();
        As[lr][lk + 0] = av.x; As[lr][lk + 1] = av.y;
        As[lr][lk + 2] = av.z; As[lr][lk + 3] = av.w;
        Bs[lr][lk + 0] = bv.x; Bs[lr][lk + 1] = bv.y;
        Bs[lr][lk + 2] = bv.z; Bs[lr][lk + 3] = bv.w;
        __syncthreads();
#pragma unroll 4
        for (int kk = 0; kk < 16; ++kk) {
            double a[4], b[4];
#pragma unroll
            for (int i = 0; i < 4; ++i) a[i] = (double)As[4 * ty + i][kk];
#pragma unroll
            for (int j = 0; j < 4; ++j) b[j] = (double)Bs[4 * tx + j][kk];
#pragma unroll
            for (int i = 0; i < 4; ++i)
#pragma unroll
                for (int j = 0; j < 4; ++j) acc[i][j] = fma(a[i], b[j], acc[i][j]);
        }
    }
#pragma unroll
    for (int i = 0; i < 4; ++i)
#pragma unroll
        for (int j = 0; j < 4; ++j)
            Out[(size_t)(row0 + 4 * ty + i) * W2 + col0 + 4 * tx + j] = (float)acc[i][j];
    if (bi != bj) {
        __syncthreads();
#pragma unroll
        for (int i = 0; i < 4; ++i)
#pragma unroll
            for (int j = 0; j < 4; ++j)
                Tr[4 * tx + j][4 * ty + i] = (float)acc[i][j];
        __syncthreads();
#pragma unroll
        for (int i = 0; i < 4; ++i)
#pragma unroll
            for (int j = 0; j < 4; ++j)
                Out[(size_t)(col0 + 4 * ty + i) * W2 + row0 + 4 * tx + j] = Tr[4 * ty + i][4 * tx + j];
    }
}

// ---- Gdiag[j] = G[j][j] ----
__global__ __launch_bounds__(256) void k_gdiag(const float* __restrict__ G,
                                               float* __restrict__ Gdiag) {
    int j = blockIdx.x * 256 + threadIdx.x;
    Gdiag[j] = G[(size_t)j * W2 + j];
}

// ---- xnorm[b] = ||x_b||^2 (fp64), one wave per row ----
__global__ __launch_bounds__(64) void k_xnorm(const float* __restrict__ x,
                                              double* __restrict__ xn) {
    int b = blockIdx.x, lane = threadIdx.x;
    float4 v = *(const float4*)(x + (size_t)b * DIMD + lane * 4);
    double s = (double)v.x * v.x + (double)v.y * v.y
             + (double)v.z * v.z + (double)v.w * v.w;
#pragma unroll
    for (int st = 32; st > 0; st >>= 1) s += __shfl_down(s, st, 64);
    if (lane == 0) xn[b] = s;
}

// ---- initial argmax from Xw + bias ----
__global__ __launch_bounds__(256) void k_argmax2(
        const float* __restrict__ Xw, const float* __restrict__ bias,
        int* __restrict__ idx) {
    int n = blockIdx.x, b = blockIdx.y, j = threadIdx.x;
    __shared__ double sv[256];
    __shared__ int sk[256];
    sv[j] = (double)Xw[(size_t)b * W2 + n * CBN + j] + (double)bias[n * CBN + j];
    sk[j] = j;
    __syncthreads();
    for (int s = 128; s > 0; s >>= 1) {
        if (j < s) {
            if (sv[j + s] > sv[j] || (sv[j + s] == sv[j] && sk[j + s] < sk[j])) {
                sv[j] = sv[j + s]; sk[j] = sk[j + s];
            }
        }
        __syncthreads();
    }
    if (j == 0) idx[b * NCBK + n] = sk[0];
}

// ---- persistent fused kernel: all 5 refinement iterations for one batch row ----
__global__ __launch_bounds__(256) void k_iter5(
        const float* __restrict__ G, const float* __restrict__ Xc,
        const float* __restrict__ Gdiag, const double* __restrict__ xnorm,
        const int* __restrict__ idx0, int* __restrict__ out) {
    int b = blockIdx.x, tid = threadIdx.x;
    __shared__ float XcL[W2];                // 8 KB (iteration-invariant)
    __shared__ float GdL[W2];                // 8 KB (iteration-invariant)
    __shared__ float Dsh[28 * 256];          // 28 KB
    __shared__ float Ecr[NCBK * NCBK * 16];  // 4 KB
    __shared__ int idxL[NCBK];
    __shared__ int jm[NCBK];
    __shared__ double gmat[64], Xcj[NCBK], Sj[NCBK], jdiag[NCBK];
    __shared__ double xes_sh;
    __shared__ int changed_sh;
    __shared__ double tv[NCBK][16];
    __shared__ int tk[NCBK][16];
    __shared__ int amr[NCBK][16];
    __shared__ double l1v[4][16]; __shared__ int l1k[4][16];
    __shared__ double l2v[2][16]; __shared__ int l2k[2][16];
    __shared__ double cv[64]; __shared__ int ck[64];
    __shared__ double tmpV[16]; __shared__ int tmpK[16];

    // one-time staging: 2048 floats each = 8 floats/thread (two float4s)
    {
        *(float4*)(XcL + tid * 8)     = *(const float4*)(Xc + (size_t)b * W2 + tid * 8);
        *(float4*)(XcL + tid * 8 + 4) = *(const float4*)(Xc + (size_t)b * W2 + tid * 8 + 4);
        *(float4*)(GdL + tid * 8)     = *(const float4*)(Gdiag + tid * 8);
        *(float4*)(GdL + tid * 8 + 4) = *(const float4*)(Gdiag + tid * 8 + 4);
        if (tid < NCBK) idxL[tid] = idx0[b * NCBK + tid];
    }
    double xnb = xnorm[b];
    __syncthreads();

    for (int it = 0; it < NITR; ++it) {
        if (tid < NCBK) jm[tid] = tid * CBN + idxL[tid];
        __syncthreads();

        // ---- bulk prefetch: all 64 cost-phase G values into registers ----
        size_t rbase[NCBK];
#pragma unroll
        for (int m = 0; m < NCBK; ++m) rbase[m] = (size_t)jm[m] * W2;
        float gv[NCBK][NCBK];  // gv[n][m] = G[jm[m]][n*256+tid]
#pragma unroll
        for (int n = 0; n < NCBK; ++n)
#pragma unroll
            for (int m = 0; m < NCBK; ++m)
                gv[n][m] = G[rbase[m] + n * CBN + tid];

        if (tid < 64) gmat[tid] = (double)G[rbase[tid >> 3] + jm[tid & 7]];
        __syncthreads();
        if (tid < NCBK) {
            Xcj[tid] = (double)XcL[jm[tid]];
            jdiag[tid] = (double)GdL[jm[tid]];
        }
        __syncthreads();
        if (tid < NCBK) {
            double s = 0.0;
            for (int mp = 0; mp < NCBK; ++mp) s += gmat[mp * 8 + tid];
            Sj[tid] = s - Xcj[tid];
        }
        __syncthreads();
        if (tid == 0) {
            double e = xnb;
            for (int m = 0; m < NCBK; ++m) e += Sj[m] - Xcj[m];
            xes_sh = e;
        }
        __syncthreads();

        // ---- cost phase: 8 sorts back-to-back, data all in registers/LDS ----
#pragma unroll
        for (int n = 0; n < NCBK; ++n) {
            int kp = n * CBN + tid;
            double s = -(double)XcL[kp];
            double gjn = 0.0;
#pragma unroll
            for (int m = 0; m < NCBK; ++m) {
                double g = (double)gv[n][m];
                s += g;
                if (m == n) gjn = g;
            }
            double cost = (xes_sh - 2.0 * Sj[n] + jdiag[n]) + 2.0 * (s - gjn) + (double)GdL[kp];
            top16_256(cost, tid, tid, cv, ck, tv[n], tk[n]);
        }
        if (tid < 128) { int m = tid >> 4, i = tid & 15; amr[m][i] = m * CBN + tk[m][i]; }
        __syncthreads();

        // ---- Ecr via G symmetry (rows jm are L2-warm from cost loads) ----
        for (int t = tid; t < NCBK * NCBK * 16; t += 256) {
            int m = t >> 7, nn = (t >> 4) & 7, ii = t & 15;
            Ecr[t] = G[(size_t)jm[nn] * W2 + amr[m][ii]];
        }
        __syncthreads();

        // ---- D-tiles: prefetch 28 scattered values, then combine ----
        {
            int i = tid >> 4, j = tid & 15;
            int ar[NCBK], ac[NCBK];
#pragma unroll
            for (int m = 0; m < NCBK; ++m) { ar[m] = amr[m][i]; ac[m] = amr[m][j]; }
            float dreg[28];
#pragma unroll
            for (int p = 0; p < 28; ++p)
                dreg[p] = G[(size_t)ar[PM28[p]] * W2 + ac[PN28[p]]];
#pragma unroll
            for (int p = 0; p < 28; ++p) {
                int m = PM28[p], n = PN28[p];
                double v = (double)dreg[p]
                         - (double)Ecr[m * 128 + n * 16 + i]
                         - (double)Ecr[n * 128 + m * 16 + j]
                         + gmat[m * 8 + n];
                Dsh[p * 256 + tid] = (float)v;
            }
        }
        __syncthreads();
        double xes = xes_sh;

        // ---- tournament ----
        for (int g = 0; g < 4; ++g) {
            int i = tid >> 4, j = tid & 15;
            double val = tv[2 * g][i] + tv[2 * g + 1][j] - xes
                       + 2.0 * (double)Dsh[pidx(2 * g, 2 * g + 1) * 256 + tid];
            top16_256(val, tid, tid, cv, ck, l1v[g], l1k[g]);
        }
        for (int G2 = 0; G2 < 2; ++G2) {
            int a = tid >> 4, b2 = tid & 15;
            int pe = l1k[2 * G2][a], po = l1k[2 * G2 + 1][b2];
            int ie = pe >> 4, io = pe & 15, je = po >> 4, jo = po & 15;
            int c0 = 4 * G2, c1 = 4 * G2 + 1, c2 = 4 * G2 + 2, c3 = 4 * G2 + 3;
            double cross = (double)Dsh[pidx(c0, c2) * 256 + ie * 16 + je]
                         + (double)Dsh[pidx(c0, c3) * 256 + ie * 16 + jo]
                         + (double)Dsh[pidx(c1, c2) * 256 + io * 16 + je]
                         + (double)Dsh[pidx(c1, c3) * 256 + io * 16 + jo];
            double val = l1v[2 * G2][a] + l1v[2 * G2 + 1][b2] - xes + 2.0 * cross;
            top16_256(val, tid, tid, cv, ck, tmpV, tmpK);
            if (tid < 16) {
                l2v[G2][tid] = tmpV[tid];
                int kk = tmpK[tid];
                l2k[G2][tid] = (l1k[2 * G2][kk >> 4] << 8) | l1k[2 * G2 + 1][kk & 15];
            }
            __syncthreads();
        }
        {
            int a = tid >> 4, b2 = tid & 15;
            int p0 = l2k[0][a], p1 = l2k[1][b2];
            int se[4] = { (p0 >> 12) & 15, (p0 >> 8) & 15, (p0 >> 4) & 15, p0 & 15 };
            int so[4] = { (p1 >> 12) & 15, (p1 >> 8) & 15, (p1 >> 4) & 15, p1 & 15 };
            double cross = 0.0;
#pragma unroll
            for (int mm = 0; mm < 4; ++mm)
#pragma unroll
                for (int q = 0; q < 4; ++q)
                    cross += (double)Dsh[pidx(mm, 4 + q) * 256 + se[mm] * 16 + so[q]];
            double val = l2v[0][a] + l2v[1][b2] - xes + 2.0 * cross;
            argmin_256(val, tid, tid, cv, ck, tmpV, tmpK);
            if (tid == 0) {
                int k = tmpK[0];
                int a0 = k >> 4, b0 = k & 15;
                int p0w = l2k[0][a0], p1w = l2k[1][b0];
                int sl[8] = { (p0w >> 12) & 15, (p0w >> 8) & 15, (p0w >> 4) & 15, p0w & 15,
                              (p1w >> 12) & 15, (p1w >> 8) & 15, (p1w >> 4) & 15, p1w & 15 };
                int changed = 0;
                for (int n = 0; n < NCBK; ++n) {
                    int ci = tk[n][sl[n]];
                    if (ci != idxL[n]) changed = 1;
                    idxL[n] = ci;
                }
                changed_sh = changed;
            }
        }
        __syncthreads();
        if (!changed_sh) break;
    }
    if (tid < NCBK) out[b * NCBK + tid] = idxL[tid];
}

extern "C" void kernel_launch(void* const* d_in, const int* in_sizes, int n_in,
                              void* d_out, int out_size, void* d_ws, size_t ws_size,
                              hipStream_t stream) {
    const float* x    = (const float*)d_in[0];  // (512, 256)
    const float* w    = (const float*)d_in[1];  // (2048, 256)
    const float* bias = (const float*)d_in[2];  // (2048,)
    const float* c    = (const float*)d_in[3];  // (2048, 256)
    int* out = (int*)d_out;                     // (512, 8) int32
    char* ws = (char*)d_ws;

    // workspace layout (~25.2 MB, fp32 tables)
    float*  G     = (float*) (ws);               // 2048*2048*4 = 16,777,216
    float*  Xc    = (float*) (ws + 16777216);    // 512*2048*4 = 4,194,304
    float*  Xw    = (float*) (ws + 20971520);    // 512*2048*4 = 4,194,304
    float*  Gdiag = (float*) (ws + 25165824);    // 2048*4     = 8,192
    int*    idx   = (int*)   (ws + 25174016);    // 512*8*4    = 16,384
    double* xnorm = (double*)(ws + 25190400);    // 512*8      = 4,096

    k_gemm_nt<<<dim3(32, 8), 256, 0, stream>>>(x, w, Xw, W2);
    k_gemm_nt<<<dim3(32, 8), 256, 0, stream>>>(x, c, Xc, W2);
    k_gemm_sym<<<528, 256, 0, stream>>>(c, G);
    k_gdiag<<<8, 256, 0, stream>>>(G, Gdiag);
    k_xnorm<<<NB, 64, 0, stream>>>(x, xnorm);
    k_argmax2<<<dim3(NCBK, NB), 256, 0, stream>>>(Xw, bias, idx);

    k_iter5<<<NB, 256, 0, stream>>>(G, Xc, Gdiag, xnorm, idx, out);
}